// Round 6
// baseline (599.780 us; speedup 1.0000x reference)
//
#include <hip/hip_runtime.h>
#include <math.h>

#define HIDDEN   1024
#define HEADS    16
#define HEAD_DIM 64
#define BATCH    4
#define SEQ      4096
#define M_TOTAL  (BATCH * SEQ)          // 16384
#define FFT_N    4096
#define WSZ      ((size_t)HIDDEN * HIDDEN)
#define PI2      6.28318530717958647692f

typedef short  s16x8 __attribute__((ext_vector_type(8)));   // 8 bf16 = 4 VGPR (MFMA A/B frag)
typedef float  f32x4 __attribute__((ext_vector_type(4)));   // MFMA C/D frag

#if defined(__has_builtin)
#if __has_builtin(__builtin_amdgcn_global_load_lds)
#define HAVE_GLL 1
#else
#define HAVE_GLL 0
#endif
#else
#define HAVE_GLL 0
#endif

#if HAVE_GLL
// async global->LDS, 16B/lane. dest = wave-uniform base + lane*16 (linear).
__device__ __forceinline__ void gload16(const void* g, void* l) {
    __builtin_amdgcn_global_load_lds(
        (const __attribute__((address_space(1))) unsigned int*)g,
        (__attribute__((address_space(3))) unsigned int*)l,
        16, 0, 0);
}
#endif

// truncation split: x = hi + lo, both bf16 (hi = top 16 bits; lo = bf16(x - hi))
__device__ __forceinline__ void split1(float v, ushort& h, ushort& l) {
    unsigned u = __float_as_uint(v);
    h = (ushort)(u >> 16);
    float hif = __uint_as_float(u & 0xffff0000u);
    float lof = v - hif;
    l = (ushort)(__float_as_uint(lof) >> 16);
}

// ---------------------------------------------------------------------------
// Pre-split: fp32 -> bf16 hi/lo planes. 8 elems/thread, exact-multiple grids.
// ---------------------------------------------------------------------------
__global__ __launch_bounds__(256) void split_kernel(
    const float* __restrict__ src, ushort* __restrict__ h,
    ushort* __restrict__ l)
{
    const size_t i = ((size_t)blockIdx.x * 256 + threadIdx.x) * 8;
    float4 v0 = *(const float4*)(src + i);
    float4 v1 = *(const float4*)(src + i + 4);
    const float vv[8] = {v0.x, v0.y, v0.z, v0.w, v1.x, v1.y, v1.z, v1.w};
    s16x8 hv, lv;
    #pragma unroll
    for (int e = 0; e < 8; ++e) {
        ushort hh, ll; split1(vv[e], hh, ll);
        hv[e] = (short)hh; lv[e] = (short)ll;
    }
    *(s16x8*)(h + i) = hv;
    *(s16x8*)(l + i) = lv;
}

// ---------------------------------------------------------------------------
// GEMM A (MFMA): fused QKV projection, stores C^T: ct[n][m].
// PS=1: staging from pre-split bf16 planes (global_load_lds w/ pre-swizzled
// source chunk, or reg copies). PS=0: validated r5 in-kernel-split path.
// ---------------------------------------------------------------------------
template<int PS>
__global__ __launch_bounds__(256) void gemm_qkv_mfma(
    const float* __restrict__ x,
    const ushort* __restrict__ xh, const ushort* __restrict__ xl,
    const float* __restrict__ Wq, const float* __restrict__ Wk,
    const float* __restrict__ Wv,
    const ushort* __restrict__ wh, const ushort* __restrict__ wl,
    const float* __restrict__ bq, const float* __restrict__ bk,
    const float* __restrict__ bv,
    float* __restrict__ qkvt)
{
    __shared__ ushort Ah[128][32], Al[128][32];
    __shared__ ushort Bh[128][32], Bl[128][32];

    const int tid  = threadIdx.x;
    const int lane = tid & 63;
    const int w    = tid >> 6;
    const int m0   = blockIdx.x * 128;
    const int p    = blockIdx.y >> 3;
    const int n0   = (blockIdx.y & 7) * 128;

    const float* __restrict__ W    = (p == 0) ? Wq : (p == 1 ? Wk : Wv);
    const float* __restrict__ bias = (p == 0) ? bq : (p == 1 ? bk : bv);
    const ushort* __restrict__ whp = wh + (size_t)p * WSZ;
    const ushort* __restrict__ wlp = wl + (size_t)p * WSZ;
    float* __restrict__ ct = qkvt + (size_t)p * HIDDEN * M_TOTAL;

    const int fr = lane & 15;
    const int fc = lane >> 4;
    const int cc = (fc ^ (fr & 3)) * 8;

    f32x4 acc[2][8];
    #pragma unroll
    for (int i = 0; i < 2; ++i)
        #pragma unroll
        for (int j = 0; j < 8; ++j)
            acc[i][j] = (f32x4){0.f, 0.f, 0.f, 0.f};

    for (int ks = 0; ks < HIDDEN / 32; ++ks) {
        const int k0 = ks * 32;
        __syncthreads();
        if constexpr (PS) {
#if HAVE_GLL
            #pragma unroll
            for (int t = 0; t < 2; ++t) {
                const int s   = tid + t * 256;
                const int row = s >> 2;
                const int chS = (s & 3) ^ (row & 3);     // pre-swizzled source
                const size_t gw = (size_t)(n0 + row) * HIDDEN + k0 + chS * 8;
                const size_t gx = (size_t)(m0 + row) * HIDDEN + k0 + chS * 8;
                const size_t wb = (size_t)(t * 256 + (tid & 0xC0)) * 8;
                gload16(whp + gw, (ushort*)Ah + wb);
                gload16(wlp + gw, (ushort*)Al + wb);
                gload16(xh + gx, (ushort*)Bh + wb);
                gload16(xl + gx, (ushort*)Bl + wb);
            }
#else
            #pragma unroll
            for (int t = 0; t < 2; ++t) {
                const int s   = tid + t * 256;
                const int row = s >> 2;
                const int ch  = s & 3;
                const int cs  = (ch ^ (row & 3)) * 8;
                const size_t gw = (size_t)(n0 + row) * HIDDEN + k0 + ch * 8;
                const size_t gx = (size_t)(m0 + row) * HIDDEN + k0 + ch * 8;
                *(s16x8*)&Ah[row][cs] = *(const s16x8*)(whp + gw);
                *(s16x8*)&Al[row][cs] = *(const s16x8*)(wlp + gw);
                *(s16x8*)&Bh[row][cs] = *(const s16x8*)(xh + gx);
                *(s16x8*)&Bl[row][cs] = *(const s16x8*)(xl + gx);
            }
#endif
        } else {
            #pragma unroll
            for (int t = 0; t < 2; ++t) {
                const int s   = tid + t * 256;
                const int row = s >> 2;
                const int ch  = s & 3;
                const int cs  = (ch ^ (row & 3)) * 8;
                {
                    const float* g = W + (size_t)(n0 + row) * HIDDEN + k0 + ch * 8;
                    float4 v0 = *(const float4*)g;
                    float4 v1 = *(const float4*)(g + 4);
                    const float vv[8] = {v0.x, v0.y, v0.z, v0.w, v1.x, v1.y, v1.z, v1.w};
                    s16x8 hv, lv;
                    #pragma unroll
                    for (int e = 0; e < 8; ++e) {
                        ushort h, l; split1(vv[e], h, l);
                        hv[e] = (short)h; lv[e] = (short)l;
                    }
                    *(s16x8*)&Ah[row][cs] = hv;
                    *(s16x8*)&Al[row][cs] = lv;
                }
                {
                    const float* g = x + (size_t)(m0 + row) * HIDDEN + k0 + ch * 8;
                    float4 v0 = *(const float4*)g;
                    float4 v1 = *(const float4*)(g + 4);
                    const float vv[8] = {v0.x, v0.y, v0.z, v0.w, v1.x, v1.y, v1.z, v1.w};
                    s16x8 hv, lv;
                    #pragma unroll
                    for (int e = 0; e < 8; ++e) {
                        ushort h, l; split1(vv[e], h, l);
                        hv[e] = (short)h; lv[e] = (short)l;
                    }
                    *(s16x8*)&Bh[row][cs] = hv;
                    *(s16x8*)&Bl[row][cs] = lv;
                }
            }
        }
        __syncthreads();
        s16x8 a_h[2], a_l[2];
        #pragma unroll
        for (int i = 0; i < 2; ++i) {
            const int R = w * 32 + i * 16 + fr;
            a_h[i] = *(const s16x8*)&Ah[R][cc];
            a_l[i] = *(const s16x8*)&Al[R][cc];
        }
        #pragma unroll
        for (int j = 0; j < 8; ++j) {
            const int R = j * 16 + fr;
            const s16x8 b_h = *(const s16x8*)&Bh[R][cc];
            const s16x8 b_l = *(const s16x8*)&Bl[R][cc];
            #pragma unroll
            for (int i = 0; i < 2; ++i) {
                acc[i][j] = __builtin_amdgcn_mfma_f32_16x16x32_bf16(a_h[i], b_h, acc[i][j], 0, 0, 0);
                acc[i][j] = __builtin_amdgcn_mfma_f32_16x16x32_bf16(a_h[i], b_l, acc[i][j], 0, 0, 0);
                acc[i][j] = __builtin_amdgcn_mfma_f32_16x16x32_bf16(a_l[i], b_h, acc[i][j], 0, 0, 0);
            }
        }
    }

    const int rq = lane >> 4;
    #pragma unroll
    for (int i = 0; i < 2; ++i) {
        #pragma unroll
        for (int r = 0; r < 4; ++r) {
            const int n = n0 + w * 32 + i * 16 + rq * 4 + r;
            const float bv = bias[n];
            float* dst = ct + (size_t)n * M_TOTAL + m0;
            #pragma unroll
            for (int j = 0; j < 8; ++j)
                dst[j * 16 + fr] = acc[i][j][r] + bv;
        }
    }
}

// ---------------------------------------------------------------------------
// Radix-16 FFT machinery (UNCHANGED, validated r5)
// ---------------------------------------------------------------------------
__device__ __forceinline__ float2 cmul(float2 a, float2 b) {
    return {a.x*b.x - a.y*b.y, a.x*b.y + a.y*b.x};
}

__device__ __forceinline__ int phys(int p) { return p ^ ((p >> 4) & 15); }

template<int DIR>
__device__ __forceinline__ void dft16(const float2* x, float2* X) {
    float2 t[16];
    #pragma unroll
    for (int n0 = 0; n0 < 4; ++n0) {
        float2 a = x[n0], b = x[n0+4], c = x[n0+8], d = x[n0+12];
        float2 s0 = {a.x+c.x, a.y+c.y}, s1 = {a.x-c.x, a.y-c.y};
        float2 s2 = {b.x+d.x, b.y+d.y}, s3 = {b.x-d.x, b.y-d.y};
        t[n0*4+0] = {s0.x+s2.x, s0.y+s2.y};
        t[n0*4+2] = {s0.x-s2.x, s0.y-s2.y};
        if (DIR < 0) {
            t[n0*4+1] = {s1.x+s3.y, s1.y-s3.x};
            t[n0*4+3] = {s1.x-s3.y, s1.y+s3.x};
        } else {
            t[n0*4+1] = {s1.x-s3.y, s1.y+s3.x};
            t[n0*4+3] = {s1.x+s3.y, s1.y-s3.x};
        }
    }
    const float C1 = 0.92387953251128674f;
    const float S1_ = 0.38268343236508978f;
    const float R2 = 0.70710678118654752f;
    #define TW(idx, cc_, ss_) t[idx] = cmul(t[idx], (float2){cc_, DIR*(ss_)})
    TW(1*4+1, C1, S1_);   TW(1*4+2, R2, R2);    TW(1*4+3, S1_, C1);
    TW(2*4+1, R2, R2);    TW(2*4+2, 0.f, 1.f);  TW(2*4+3, -R2, R2);
    TW(3*4+1, S1_, C1);   TW(3*4+2, -R2, R2);   TW(3*4+3, -C1, -S1_);
    #undef TW
    #pragma unroll
    for (int k0 = 0; k0 < 4; ++k0) {
        float2 a = t[0+k0], b = t[4+k0], c = t[8+k0], d = t[12+k0];
        float2 s0 = {a.x+c.x, a.y+c.y}, s1 = {a.x-c.x, a.y-c.y};
        float2 s2 = {b.x+d.x, b.y+d.y}, s3 = {b.x-d.x, b.y-d.y};
        X[k0+0]  = {s0.x+s2.x, s0.y+s2.y};
        X[k0+8]  = {s0.x-s2.x, s0.y-s2.y};
        if (DIR < 0) {
            X[k0+4]  = {s1.x+s3.y, s1.y-s3.x};
            X[k0+12] = {s1.x-s3.y, s1.y+s3.x};
        } else {
            X[k0+4]  = {s1.x-s3.y, s1.y+s3.x};
            X[k0+12] = {s1.x+s3.y, s1.y-s3.x};
        }
    }
}

__device__ __forceinline__ void twiddle_apply(float2* y, float ang) {
    float s, c;
    __sincosf(ang, &s, &c);
    const float2 base = {c, s};
    float2 w = base;
    #pragma unroll
    for (int u = 1; u < 16; ++u) {
        y[u] = cmul(y[u], w);
        w = cmul(w, base);
    }
}

__global__ __launch_bounds__(256) void fft_attn_kernel(
    const float* __restrict__ qt, const float* __restrict__ kt,
    const float* __restrict__ vt, float* __restrict__ ot)
{
    __shared__ float2 bufA[FFT_N];
    __shared__ float2 bufB[FFT_N];

    const int tid = threadIdx.x;
    const int bid = blockIdx.x;
    const int n   = bid >> 2;
    const int b   = bid & 3;

    const size_t off = (size_t)n * M_TOTAL + (size_t)b * SEQ;
    const float* qrow = qt + off;
    const float* krow = kt + off;
    const float* vrow = vt + off;
    float*       orow = ot + off;

    {
        const int q = tid;
        float2 xA[16], xB[16], yA[16], yB[16];
        #pragma unroll
        for (int r = 0; r < 16; ++r) {
            xA[r] = { qrow[q + 256*r], krow[q + 256*r] };
            xB[r] = { vrow[q + 256*r], 0.f };
        }
        dft16<-1>(xA, yA);
        dft16<-1>(xB, yB);
        const float ang = -PI2 * (float)q / 4096.f;
        twiddle_apply(yA, ang);
        twiddle_apply(yB, ang);
        #pragma unroll
        for (int u = 0; u < 16; ++u) {
            bufA[phys(q + 256*u)] = yA[u];
            bufB[phys(q + 256*u)] = yB[u];
        }
    }
    __syncthreads();
    {
        const int blk = tid >> 4, a = tid & 15;
        const int base = 256*blk + a;
        float2 xA[16], xB[16], yA[16], yB[16];
        #pragma unroll
        for (int c = 0; c < 16; ++c) {
            xA[c] = bufA[phys(base + 16*c)];
            xB[c] = bufB[phys(base + 16*c)];
        }
        dft16<-1>(xA, yA);
        dft16<-1>(xB, yB);
        const float ang = -PI2 * (float)a / 256.f;
        twiddle_apply(yA, ang);
        twiddle_apply(yB, ang);
        #pragma unroll
        for (int c = 0; c < 16; ++c) {
            bufA[phys(base + 16*c)] = yA[c];
            bufB[phys(base + 16*c)] = yB[c];
        }
    }
    __syncthreads();
    {
        const int blk = tid >> 4, c = tid & 15;
        const int base = 256*blk + 16*c;
        float2 xA[16], xB[16], yA[16], yB[16];
        #pragma unroll
        for (int a2 = 0; a2 < 16; ++a2) {
            xA[a2] = bufA[phys(base + a2)];
            xB[a2] = bufB[phys(base + a2)];
        }
        dft16<-1>(xA, yA);
        dft16<-1>(xB, yB);
        #pragma unroll
        for (int d = 0; d < 16; ++d) {
            bufA[phys(base + d)] = yA[d];
            bufB[phys(base + d)] = yB[d];
        }
    }
    __syncthreads();
    #pragma unroll
    for (int it = 0; it < 16; ++it) {
        const int p  = tid + it * 256;
        const int j  = ((p & 15) << 8) | (p & 0xF0) | (p >> 8);
        const int jn = (FFT_N - j) & (FFT_N - 1);
        const int pn = ((jn & 15) << 8) | (jn & 0xF0) | (jn >> 8);
        const float2 Zj = bufA[phys(p)];
        const float2 Zn = bufA[phys(pn)];
        const float2 Q = { 0.5f*(Zj.x + Zn.x), 0.5f*(Zj.y - Zn.y) };
        const float2 K = { 0.5f*(Zj.y + Zn.y), -0.5f*(Zj.x - Zn.x) };
        const float2 G = { Q.x*K.x + Q.y*K.y, Q.y*K.x - Q.x*K.y };
        const float2 V = bufB[phys(p)];
        bufB[phys(p)] = { G.x*V.x - G.y*V.y, G.x*V.y + G.y*V.x };
    }
    __syncthreads();
    {
        const int blk = tid >> 4, c = tid & 15;
        const int base = 256*blk + 16*c;
        float2 x[16], y[16];
        #pragma unroll
        for (int d = 0; d < 16; ++d) x[d] = bufB[phys(base + d)];
        dft16<1>(x, y);
        #pragma unroll
        for (int p0 = 0; p0 < 16; ++p0) bufB[phys(base + p0)] = y[p0];
    }
    __syncthreads();
    {
        const int blk = tid >> 4, p0 = tid & 15;
        const int base = 256*blk + p0;
        float2 x[16], y[16];
        #pragma unroll
        for (int c = 0; c < 16; ++c) x[c] = bufB[phys(base + 16*c)];
        twiddle_apply(x, PI2 * (float)p0 / 256.f);
        dft16<1>(x, y);
        #pragma unroll
        for (int p1 = 0; p1 < 16; ++p1) bufB[phys(base + 16*p1)] = y[p1];
    }
    __syncthreads();
    {
        const int qq = tid;
        float2 x[16], y[16];
        #pragma unroll
        for (int t = 0; t < 16; ++t) x[t] = bufB[phys(qq + 256*t)];
        twiddle_apply(x, PI2 * (float)qq / 4096.f);
        dft16<1>(x, y);
        const float scale = 0.125f / 4096.f;
        #pragma unroll
        for (int p2 = 0; p2 < 16; ++p2)
            orow[qq + 256*p2] = y[p2].x * scale;
    }
}

// ---------------------------------------------------------------------------
// Transpose + split (UNCHANGED, validated r4/r5)
// ---------------------------------------------------------------------------
__global__ __launch_bounds__(256) void transpose_split_kernel(
    const float* __restrict__ ot, ushort* __restrict__ oth,
    ushort* __restrict__ otl)
{
    __shared__ float tile[64][65];
    const int tid = threadIdx.x;
    const int m0  = blockIdx.x * 64;
    const int n0  = blockIdx.y * 64;
    const int r   = tid >> 4;
    const int c   = tid & 15;

    #pragma unroll
    for (int rr = 0; rr < 4; ++rr) {
        const int nl = r + rr * 16;
        float4 v = *(const float4*)(ot + (size_t)(n0 + nl) * M_TOTAL + m0 + c * 4);
        tile[nl][c * 4 + 0] = v.x; tile[nl][c * 4 + 1] = v.y;
        tile[nl][c * 4 + 2] = v.z; tile[nl][c * 4 + 3] = v.w;
    }
    __syncthreads();
    #pragma unroll
    for (int rr = 0; rr < 4; ++rr) {
        const int ml = r + rr * 16;
        ushort4 h, l;
        split1(tile[c * 4 + 0][ml], h.x, l.x);
        split1(tile[c * 4 + 1][ml], h.y, l.y);
        split1(tile[c * 4 + 2][ml], h.z, l.z);
        split1(tile[c * 4 + 3][ml], h.w, l.w);
        *(ushort4*)(oth + (size_t)(m0 + ml) * HIDDEN + n0 + c * 4) = h;
        *(ushort4*)(otl + (size_t)(m0 + ml) * HIDDEN + n0 + c * 4) = l;
    }
}

// ---------------------------------------------------------------------------
// GEMM C (MFMA): out[m][n] = sum_k ot^T[m][k] * Wo[n][k] + bo[n]
// ---------------------------------------------------------------------------
template<int PS>
__global__ __launch_bounds__(256) void gemm_out_mfma(
    const ushort* __restrict__ oth, const ushort* __restrict__ otl,
    const float* __restrict__ Wo,
    const ushort* __restrict__ woh, const ushort* __restrict__ wol,
    const float* __restrict__ bo, float* __restrict__ out)
{
    __shared__ ushort Ah[128][32], Al[128][32];
    __shared__ ushort Bh[128][32], Bl[128][32];

    const int tid  = threadIdx.x;
    const int lane = tid & 63;
    const int w    = tid >> 6;
    const int m0   = blockIdx.x * 128;
    const int n0   = blockIdx.y * 128;

    const int fr = lane & 15;
    const int fc = lane >> 4;
    const int cc = (fc ^ (fr & 3)) * 8;

    f32x4 acc[2][8];
    #pragma unroll
    for (int i = 0; i < 2; ++i)
        #pragma unroll
        for (int j = 0; j < 8; ++j)
            acc[i][j] = (f32x4){0.f, 0.f, 0.f, 0.f};

    for (int ks = 0; ks < HIDDEN / 32; ++ks) {
        const int k0 = ks * 32;
        __syncthreads();
        if constexpr (PS) {
#if HAVE_GLL
            #pragma unroll
            for (int t = 0; t < 2; ++t) {
                const int s   = tid + t * 256;
                const int row = s >> 2;
                const int chS = (s & 3) ^ (row & 3);
                const size_t ga = (size_t)(m0 + row) * HIDDEN + k0 + chS * 8;
                const size_t gb = (size_t)(n0 + row) * HIDDEN + k0 + chS * 8;
                const size_t wb = (size_t)(t * 256 + (tid & 0xC0)) * 8;
                gload16(oth + ga, (ushort*)Ah + wb);
                gload16(otl + ga, (ushort*)Al + wb);
                gload16(woh + gb, (ushort*)Bh + wb);
                gload16(wol + gb, (ushort*)Bl + wb);
            }
#else
            #pragma unroll
            for (int t = 0; t < 2; ++t) {
                const int s   = tid + t * 256;
                const int row = s >> 2;
                const int ch  = s & 3;
                const int cs  = (ch ^ (row & 3)) * 8;
                const size_t ga = (size_t)(m0 + row) * HIDDEN + k0 + ch * 8;
                const size_t gb = (size_t)(n0 + row) * HIDDEN + k0 + ch * 8;
                *(s16x8*)&Ah[row][cs] = *(const s16x8*)(oth + ga);
                *(s16x8*)&Al[row][cs] = *(const s16x8*)(otl + ga);
                *(s16x8*)&Bh[row][cs] = *(const s16x8*)(woh + gb);
                *(s16x8*)&Bl[row][cs] = *(const s16x8*)(wol + gb);
            }
#endif
        } else {
            #pragma unroll
            for (int t = 0; t < 2; ++t) {
                const int s   = tid + t * 256;
                const int row = s >> 2;
                const int ch  = s & 3;
                const int cs  = (ch ^ (row & 3)) * 8;
                {
                    const size_t g = (size_t)(m0 + row) * HIDDEN + k0 + ch * 8;
                    *(s16x8*)&Ah[row][cs] = *(const s16x8*)(oth + g);
                    *(s16x8*)&Al[row][cs] = *(const s16x8*)(otl + g);
                }
                {
                    const float* g = Wo + (size_t)(n0 + row) * HIDDEN + k0 + ch * 8;
                    float4 v0 = *(const float4*)g;
                    float4 v1 = *(const float4*)(g + 4);
                    const float vv[8] = {v0.x, v0.y, v0.z, v0.w, v1.x, v1.y, v1.z, v1.w};
                    s16x8 hv, lv;
                    #pragma unroll
                    for (int e = 0; e < 8; ++e) {
                        ushort h, l; split1(vv[e], h, l);
                        hv[e] = (short)h; lv[e] = (short)l;
                    }
                    *(s16x8*)&Bh[row][cs] = hv;
                    *(s16x8*)&Bl[row][cs] = lv;
                }
            }
        }
        __syncthreads();
        s16x8 a_h[2], a_l[2];
        #pragma unroll
        for (int i = 0; i < 2; ++i) {
            const int R = w * 32 + i * 16 + fr;
            a_h[i] = *(const s16x8*)&Ah[R][cc];
            a_l[i] = *(const s16x8*)&Al[R][cc];
        }
        #pragma unroll
        for (int j = 0; j < 8; ++j) {
            const int R = j * 16 + fr;
            const s16x8 b_h = *(const s16x8*)&Bh[R][cc];
            const s16x8 b_l = *(const s16x8*)&Bl[R][cc];
            #pragma unroll
            for (int i = 0; i < 2; ++i) {
                acc[i][j] = __builtin_amdgcn_mfma_f32_16x16x32_bf16(a_h[i], b_h, acc[i][j], 0, 0, 0);
                acc[i][j] = __builtin_amdgcn_mfma_f32_16x16x32_bf16(a_h[i], b_l, acc[i][j], 0, 0, 0);
                acc[i][j] = __builtin_amdgcn_mfma_f32_16x16x32_bf16(a_l[i], b_h, acc[i][j], 0, 0, 0);
            }
        }
    }

    const int rq = lane >> 4;
    float bo_v[8];
    #pragma unroll
    for (int j = 0; j < 8; ++j) bo_v[j] = bo[n0 + j * 16 + fr];
    #pragma unroll
    for (int i = 0; i < 2; ++i) {
        #pragma unroll
        for (int r = 0; r < 4; ++r) {
            const int m = m0 + w * 32 + i * 16 + rq * 4 + r;
            float* dst = out + (size_t)m * HIDDEN + n0;
            #pragma unroll
            for (int j = 0; j < 8; ++j)
                dst[j * 16 + fr] = acc[i][j][r] + bo_v[j];
        }
    }
}

// ---------------------------------------------------------------------------
extern "C" void kernel_launch(void* const* d_in, const int* in_sizes, int n_in,
                              void* d_out, int out_size, void* d_ws, size_t ws_size,
                              hipStream_t stream)
{
    const float* x  = (const float*)d_in[0];
    const float* Wq = (const float*)d_in[1];
    const float* bq = (const float*)d_in[2];
    const float* Wk = (const float*)d_in[3];
    const float* bk = (const float*)d_in[4];
    const float* Wv = (const float*)d_in[5];
    const float* bv = (const float*)d_in[6];
    const float* Wo = (const float*)d_in[7];
    const float* bo = (const float*)d_in[8];
    float* out = (float*)d_out;

    const size_t plane = (size_t)HIDDEN * M_TOTAL;   // 16.7M elements
    char* base = (char*)d_ws;
    float* qt = (float*)base;
    float* kt = qt + plane;
    float* vt = kt + plane;
    float* ot = qt;                    // FFT output aliases q plane
    ushort* oth = (ushort*)kt;         // transposed bf16 hi plane (dead k plane)
    ushort* otl = (ushort*)vt;         // lo plane (dead v plane)

    // pre-split planes beyond the 3 fp32 planes
    ushort* xh  = (ushort*)(base + plane * 12);
    ushort* xl  = xh + plane;
    ushort* wqh = xl + plane;          // [3][1024][1024] hi
    ushort* wql = wqh + 3 * WSZ;       // [3][1024][1024] lo
    ushort* woh = wql + 3 * WSZ;
    ushort* wol = woh + WSZ;

    const size_t need = plane * 12            // qt,kt,vt fp32
                      + plane * 2 * 2         // xh,xl
                      + WSZ * 2 * 8;          // wqh,wql(3 each) + woh,wol
    const bool PS = (ws_size >= need);

    if (PS) {
        split_kernel<<<(unsigned)(plane / 2048), 256, 0, stream>>>(x, xh, xl);
        split_kernel<<<(unsigned)(WSZ / 2048), 256, 0, stream>>>(Wq, wqh, wql);
        split_kernel<<<(unsigned)(WSZ / 2048), 256, 0, stream>>>(Wk, wqh + WSZ, wql + WSZ);
        split_kernel<<<(unsigned)(WSZ / 2048), 256, 0, stream>>>(Wv, wqh + 2 * WSZ, wql + 2 * WSZ);
        split_kernel<<<(unsigned)(WSZ / 2048), 256, 0, stream>>>(Wo, woh, wol);
        gemm_qkv_mfma<1><<<dim3(M_TOTAL / 128, 24), 256, 0, stream>>>(
            x, xh, xl, Wq, Wk, Wv, wqh, wql, bq, bk, bv, qt);
    } else {
        gemm_qkv_mfma<0><<<dim3(M_TOTAL / 128, 24), 256, 0, stream>>>(
            x, xh, xl, Wq, Wk, Wv, wqh, wql, bq, bk, bv, qt);
    }

    fft_attn_kernel<<<dim3(HIDDEN * BATCH), 256, 0, stream>>>(qt, kt, vt, ot);

    transpose_split_kernel<<<dim3(M_TOTAL / 64, HIDDEN / 64), 256, 0, stream>>>(
        ot, oth, otl);

    if (PS) {
        gemm_out_mfma<1><<<dim3(M_TOTAL / 128, HIDDEN / 128), 256, 0, stream>>>(
            oth, otl, Wo, woh, wol, bo, out);
    } else {
        gemm_out_mfma<0><<<dim3(M_TOTAL / 128, HIDDEN / 128), 256, 0, stream>>>(
            oth, otl, Wo, woh, wol, bo, out);
    }
}

// Round 7
// 566.289 us; speedup vs baseline: 1.0591x; 1.0591x over previous
//
#include <hip/hip_runtime.h>
#include <hip/hip_bf16.h>
#include <math.h>

#define HIDDEN   1024
#define HEADS    16
#define HEAD_DIM 64
#define BATCH    4
#define SEQ      4096
#define M_TOTAL  (BATCH * SEQ)          // 16384
#define FFT_N    4096
#define WSZ      ((size_t)HIDDEN * HIDDEN)
#define PI2      6.28318530717958647692f

typedef short  s16x8 __attribute__((ext_vector_type(8)));   // 8 bf16 = 4 VGPR (MFMA A/B frag)
typedef float  f32x4 __attribute__((ext_vector_type(4)));   // MFMA C/D frag

#if defined(__has_builtin)
#if __has_builtin(__builtin_amdgcn_global_load_lds)
#define HAVE_GLL 1
#else
#define HAVE_GLL 0
#endif
#else
#define HAVE_GLL 0
#endif

#if HAVE_GLL
// async global->LDS, 16B/lane. lane's lds ptr = wave-uniform base + lane*16.
__device__ __forceinline__ void gload16(const void* g, void* l) {
    __builtin_amdgcn_global_load_lds(
        (const __attribute__((address_space(1))) unsigned int*)g,
        (__attribute__((address_space(3))) unsigned int*)l,
        16, 0, 0);
}
#endif

// RNE bf16 bits of f (compiler can pair into v_cvt_pk_bf16_f32)
__device__ __forceinline__ ushort bf16_rne(float f) {
    union { __hip_bfloat16 b; ushort u; } cv;
    cv.b = __float2bfloat16(f);
    return cv.u;
}

// RNE split: x = hi + lo (hi = rne(x), lo = rne(x - hi)); |lo| <= 0.5 ulp(hi)
__device__ __forceinline__ void split8_store(const float* __restrict__ g,
                                             ushort* __restrict__ hd,
                                             ushort* __restrict__ ld) {
    float4 v0 = *(const float4*)g;
    float4 v1 = *(const float4*)(g + 4);
    const float vv[8] = {v0.x, v0.y, v0.z, v0.w, v1.x, v1.y, v1.z, v1.w};
    s16x8 hv, lv;
    #pragma unroll
    for (int e = 0; e < 8; ++e) {
        const ushort h = bf16_rne(vv[e]);
        const float hf = __uint_as_float((unsigned)h << 16);
        hv[e] = (short)h;
        lv[e] = (short)bf16_rne(vv[e] - hf);
    }
    *(s16x8*)hd = hv;
    *(s16x8*)ld = lv;
}

// truncation split (kept for transpose_split, validated r4-r6)
__device__ __forceinline__ void split1(float v, ushort& h, ushort& l) {
    unsigned u = __float_as_uint(v);
    h = (ushort)(u >> 16);
    float hif = __uint_as_float(u & 0xffff0000u);
    float lof = v - hif;
    l = (ushort)(__float_as_uint(lof) >> 16);
}

// ---------------------------------------------------------------------------
// Pre-split: fp32 -> bf16 hi/lo planes (RNE). 8 elems/thread.
// ---------------------------------------------------------------------------
__global__ __launch_bounds__(256) void split_kernel(
    const float* __restrict__ src, ushort* __restrict__ h,
    ushort* __restrict__ l)
{
    const size_t i = ((size_t)blockIdx.x * 256 + threadIdx.x) * 8;
    split8_store(src + i, h + i, l + i);
}

// ---------------------------------------------------------------------------
// QKV GEMM (MFMA): stacked-W [3072][1024] x x^T -> ct[p][n][m]
// 256x256 tile, 512 thr = 8 waves (4m x 2n), wave tile 64m x 128n.
// BK=32, double-buffered LDS (128 KiB), one barrier per K-step.
// Swizzle: chunk-pos = ch ^ ((row>>1)&3)  (2-way per quarter, free).
// PS=2: A,B from pre-split planes (gload16). PS=1: A pre-split, B in-kernel
// split. PS=0: both in-kernel split.
// ---------------------------------------------------------------------------
template<int PS>
__device__ __forceinline__ void qkv2_stage(
    int tid, int k0,
    const float* __restrict__ x,
    const ushort* __restrict__ xh, const ushort* __restrict__ xl,
    const float* __restrict__ Wsel,
    const ushort* __restrict__ wh, const ushort* __restrict__ wl,
    int m0, int ng0, int n0p,
    ushort* __restrict__ Ah, ushort* __restrict__ Al,
    ushort* __restrict__ Bh, ushort* __restrict__ Bl)
{
    #pragma unroll
    for (int t = 0; t < 2; ++t) {
        const int s   = tid + t * 512;      // slot [0,1024)
        const int row = s >> 2;             // [0,256)
        const int ch  = s & 3;
        const int fsw = (row >> 1) & 3;
        // ---- A: W rows (stacked n) ----
        if constexpr (PS >= 1) {
            const size_t g = (size_t)(ng0 + row) * HIDDEN + k0 + (size_t)(ch ^ fsw) * 8;
#if HAVE_GLL
            gload16(wh + g, Ah + (size_t)s * 8);
            gload16(wl + g, Al + (size_t)s * 8);
#else
            *(s16x8*)(Ah + (size_t)s * 8) = *(const s16x8*)(wh + g);
            *(s16x8*)(Al + (size_t)s * 8) = *(const s16x8*)(wl + g);
#endif
        } else {
            const int cs = (ch ^ fsw) * 8;
            const float* g = Wsel + (size_t)(n0p + row) * HIDDEN + k0 + ch * 8;
            split8_store(g, Ah + row * 32 + cs, Al + row * 32 + cs);
        }
        // ---- B: x rows (m) ----
        if constexpr (PS >= 2) {
            const size_t g = (size_t)(m0 + row) * HIDDEN + k0 + (size_t)(ch ^ fsw) * 8;
#if HAVE_GLL
            gload16(xh + g, Bh + (size_t)s * 8);
            gload16(xl + g, Bl + (size_t)s * 8);
#else
            *(s16x8*)(Bh + (size_t)s * 8) = *(const s16x8*)(xh + g);
            *(s16x8*)(Bl + (size_t)s * 8) = *(const s16x8*)(xl + g);
#endif
        } else {
            const int cs = (ch ^ fsw) * 8;
            const float* g = x + (size_t)(m0 + row) * HIDDEN + k0 + ch * 8;
            split8_store(g, Bh + row * 32 + cs, Bl + row * 32 + cs);
        }
    }
}

__device__ __forceinline__ void qkv2_compute(
    const ushort* __restrict__ Ah, const ushort* __restrict__ Al,
    const ushort* __restrict__ Bh, const ushort* __restrict__ Bl,
    int wm, int wn, int fr, int cc, f32x4 acc[8][4])
{
    s16x8 b_h[4], b_l[4];
    #pragma unroll
    for (int mf = 0; mf < 4; ++mf) {
        const int R = wm * 64 + mf * 16 + fr;
        b_h[mf] = *(const s16x8*)(Bh + R * 32 + cc);
        b_l[mf] = *(const s16x8*)(Bl + R * 32 + cc);
    }
    #pragma unroll
    for (int nf = 0; nf < 8; ++nf) {
        const int R = wn * 128 + nf * 16 + fr;
        const s16x8 a_h = *(const s16x8*)(Ah + R * 32 + cc);
        const s16x8 a_l = *(const s16x8*)(Al + R * 32 + cc);
        #pragma unroll
        for (int mf = 0; mf < 4; ++mf) {
            acc[nf][mf] = __builtin_amdgcn_mfma_f32_16x16x32_bf16(a_h, b_h[mf], acc[nf][mf], 0, 0, 0);
            acc[nf][mf] = __builtin_amdgcn_mfma_f32_16x16x32_bf16(a_h, b_l[mf], acc[nf][mf], 0, 0, 0);
            acc[nf][mf] = __builtin_amdgcn_mfma_f32_16x16x32_bf16(a_l, b_h[mf], acc[nf][mf], 0, 0, 0);
        }
    }
}

template<int PS>
__global__ __launch_bounds__(512, 2) void gemm_qkv_mfma2(
    const float* __restrict__ x,
    const ushort* __restrict__ xh, const ushort* __restrict__ xl,
    const float* __restrict__ Wq, const float* __restrict__ Wk,
    const float* __restrict__ Wv,
    const ushort* __restrict__ wh, const ushort* __restrict__ wl,
    const float* __restrict__ bq, const float* __restrict__ bk,
    const float* __restrict__ bv,
    float* __restrict__ qkvt)
{
    __shared__ ushort Ah[2][256][32], Al[2][256][32];   // 32 KB each pair-half
    __shared__ ushort Bh[2][256][32], Bl[2][256][32];   // total 128 KB

    const int tid  = threadIdx.x;
    const int lane = tid & 63;
    const int wid  = tid >> 6;        // 0..7
    const int wm   = wid & 3;         // 4 m-waves
    const int wn   = wid >> 2;        // 2 n-waves
    const int m0   = blockIdx.x * 256;
    const int ng0  = blockIdx.y * 256;            // stacked n
    const int p    = ng0 >> 10;
    const int n0p  = ng0 & 1023;

    const float* __restrict__ Wsel = (p == 0) ? Wq : (p == 1 ? Wk : Wv);
    const float* __restrict__ bias = (p == 0) ? bq : (p == 1 ? bk : bv);
    float* __restrict__ ct = qkvt + (size_t)p * HIDDEN * M_TOTAL;

    const int fr = lane & 15;
    const int fc = lane >> 4;
    const int cc = (fc ^ ((fr >> 1) & 3)) * 8;    // row base mult of 16 -> (row>>1)&3 == (fr>>1)&3

    f32x4 acc[8][4];
    #pragma unroll
    for (int nf = 0; nf < 8; ++nf)
        #pragma unroll
        for (int mf = 0; mf < 4; ++mf)
            acc[nf][mf] = (f32x4){0.f, 0.f, 0.f, 0.f};

    qkv2_stage<PS>(tid, 0, x, xh, xl, Wsel, wh, wl, m0, ng0, n0p,
                   &Ah[0][0][0], &Al[0][0][0], &Bh[0][0][0], &Bl[0][0][0]);
    __syncthreads();

    for (int ks = 0; ks < HIDDEN / 32; ++ks) {
        const int cur = ks & 1;
        if (ks + 1 < HIDDEN / 32) {
            const int nxt = cur ^ 1;
            qkv2_stage<PS>(tid, (ks + 1) * 32, x, xh, xl, Wsel, wh, wl, m0, ng0, n0p,
                           &Ah[nxt][0][0], &Al[nxt][0][0], &Bh[nxt][0][0], &Bl[nxt][0][0]);
        }
        qkv2_compute(&Ah[cur][0][0], &Al[cur][0][0], &Bh[cur][0][0], &Bl[cur][0][0],
                     wm, wn, fr, cc, acc);
        __syncthreads();
    }

    // epilogue: D row n_local = wn*128 + nf*16 + rq*4 + r; col m_local = wm*64 + mf*16 + fr
    const int rq = lane >> 4;
    #pragma unroll
    for (int nf = 0; nf < 8; ++nf) {
        #pragma unroll
        for (int r = 0; r < 4; ++r) {
            const int nl = wn * 128 + nf * 16 + rq * 4 + r;
            const float bv = bias[n0p + nl];
            float* dst = ct + (size_t)(n0p + nl) * M_TOTAL + m0 + wm * 64;
            #pragma unroll
            for (int mf = 0; mf < 4; ++mf)
                dst[mf * 16 + fr] = acc[nf][mf][r] + bv;
        }
    }
}

// ---------------------------------------------------------------------------
// Radix-16 FFT machinery (UNCHANGED, validated r5/r6)
// ---------------------------------------------------------------------------
__device__ __forceinline__ float2 cmul(float2 a, float2 b) {
    return {a.x*b.x - a.y*b.y, a.x*b.y + a.y*b.x};
}

__device__ __forceinline__ int phys(int p) { return p ^ ((p >> 4) & 15); }

template<int DIR>
__device__ __forceinline__ void dft16(const float2* x, float2* X) {
    float2 t[16];
    #pragma unroll
    for (int n0 = 0; n0 < 4; ++n0) {
        float2 a = x[n0], b = x[n0+4], c = x[n0+8], d = x[n0+12];
        float2 s0 = {a.x+c.x, a.y+c.y}, s1 = {a.x-c.x, a.y-c.y};
        float2 s2 = {b.x+d.x, b.y+d.y}, s3 = {b.x-d.x, b.y-d.y};
        t[n0*4+0] = {s0.x+s2.x, s0.y+s2.y};
        t[n0*4+2] = {s0.x-s2.x, s0.y-s2.y};
        if (DIR < 0) {
            t[n0*4+1] = {s1.x+s3.y, s1.y-s3.x};
            t[n0*4+3] = {s1.x-s3.y, s1.y+s3.x};
        } else {
            t[n0*4+1] = {s1.x-s3.y, s1.y+s3.x};
            t[n0*4+3] = {s1.x+s3.y, s1.y-s3.x};
        }
    }
    const float C1 = 0.92387953251128674f;
    const float S1_ = 0.38268343236508978f;
    const float R2 = 0.70710678118654752f;
    #define TW(idx, cc_, ss_) t[idx] = cmul(t[idx], (float2){cc_, DIR*(ss_)})
    TW(1*4+1, C1, S1_);   TW(1*4+2, R2, R2);    TW(1*4+3, S1_, C1);
    TW(2*4+1, R2, R2);    TW(2*4+2, 0.f, 1.f);  TW(2*4+3, -R2, R2);
    TW(3*4+1, S1_, C1);   TW(3*4+2, -R2, R2);   TW(3*4+3, -C1, -S1_);
    #undef TW
    #pragma unroll
    for (int k0 = 0; k0 < 4; ++k0) {
        float2 a = t[0+k0], b = t[4+k0], c = t[8+k0], d = t[12+k0];
        float2 s0 = {a.x+c.x, a.y+c.y}, s1 = {a.x-c.x, a.y-c.y};
        float2 s2 = {b.x+d.x, b.y+d.y}, s3 = {b.x-d.x, b.y-d.y};
        X[k0+0]  = {s0.x+s2.x, s0.y+s2.y};
        X[k0+8]  = {s0.x-s2.x, s0.y-s2.y};
        if (DIR < 0) {
            X[k0+4]  = {s1.x+s3.y, s1.y-s3.x};
            X[k0+12] = {s1.x-s3.y, s1.y+s3.x};
        } else {
            X[k0+4]  = {s1.x-s3.y, s1.y+s3.x};
            X[k0+12] = {s1.x+s3.y, s1.y-s3.x};
        }
    }
}

__device__ __forceinline__ void twiddle_apply(float2* y, float ang) {
    float s, c;
    __sincosf(ang, &s, &c);
    const float2 base = {c, s};
    float2 w = base;
    #pragma unroll
    for (int u = 1; u < 16; ++u) {
        y[u] = cmul(y[u], w);
        w = cmul(w, base);
    }
}

__global__ __launch_bounds__(256) void fft_attn_kernel(
    const float* __restrict__ qt, const float* __restrict__ kt,
    const float* __restrict__ vt, float* __restrict__ ot)
{
    __shared__ float2 bufA[FFT_N];
    __shared__ float2 bufB[FFT_N];

    const int tid = threadIdx.x;
    const int bid = blockIdx.x;
    const int n   = bid >> 2;
    const int b   = bid & 3;

    const size_t off = (size_t)n * M_TOTAL + (size_t)b * SEQ;
    const float* qrow = qt + off;
    const float* krow = kt + off;
    const float* vrow = vt + off;
    float*       orow = ot + off;

    {
        const int q = tid;
        float2 xA[16], xB[16], yA[16], yB[16];
        #pragma unroll
        for (int r = 0; r < 16; ++r) {
            xA[r] = { qrow[q + 256*r], krow[q + 256*r] };
            xB[r] = { vrow[q + 256*r], 0.f };
        }
        dft16<-1>(xA, yA);
        dft16<-1>(xB, yB);
        const float ang = -PI2 * (float)q / 4096.f;
        twiddle_apply(yA, ang);
        twiddle_apply(yB, ang);
        #pragma unroll
        for (int u = 0; u < 16; ++u) {
            bufA[phys(q + 256*u)] = yA[u];
            bufB[phys(q + 256*u)] = yB[u];
        }
    }
    __syncthreads();
    {
        const int blk = tid >> 4, a = tid & 15;
        const int base = 256*blk + a;
        float2 xA[16], xB[16], yA[16], yB[16];
        #pragma unroll
        for (int c = 0; c < 16; ++c) {
            xA[c] = bufA[phys(base + 16*c)];
            xB[c] = bufB[phys(base + 16*c)];
        }
        dft16<-1>(xA, yA);
        dft16<-1>(xB, yB);
        const float ang = -PI2 * (float)a / 256.f;
        twiddle_apply(yA, ang);
        twiddle_apply(yB, ang);
        #pragma unroll
        for (int c = 0; c < 16; ++c) {
            bufA[phys(base + 16*c)] = yA[c];
            bufB[phys(base + 16*c)] = yB[c];
        }
    }
    __syncthreads();
    {
        const int blk = tid >> 4, c = tid & 15;
        const int base = 256*blk + 16*c;
        float2 xA[16], xB[16], yA[16], yB[16];
        #pragma unroll
        for (int a2 = 0; a2 < 16; ++a2) {
            xA[a2] = bufA[phys(base + a2)];
            xB[a2] = bufB[phys(base + a2)];
        }
        dft16<-1>(xA, yA);
        dft16<-1>(xB, yB);
        #pragma unroll
        for (int d = 0; d < 16; ++d) {
            bufA[phys(base + d)] = yA[d];
            bufB[phys(base + d)] = yB[d];
        }
    }
    __syncthreads();
    #pragma unroll
    for (int it = 0; it < 16; ++it) {
        const int p  = tid + it * 256;
        const int j  = ((p & 15) << 8) | (p & 0xF0) | (p >> 8);
        const int jn = (FFT_N - j) & (FFT_N - 1);
        const int pn = ((jn & 15) << 8) | (jn & 0xF0) | (jn >> 8);
        const float2 Zj = bufA[phys(p)];
        const float2 Zn = bufA[phys(pn)];
        const float2 Q = { 0.5f*(Zj.x + Zn.x), 0.5f*(Zj.y - Zn.y) };
        const float2 K = { 0.5f*(Zj.y + Zn.y), -0.5f*(Zj.x - Zn.x) };
        const float2 G = { Q.x*K.x + Q.y*K.y, Q.y*K.x - Q.x*K.y };
        const float2 V = bufB[phys(p)];
        bufB[phys(p)] = { G.x*V.x - G.y*V.y, G.x*V.y + G.y*V.x };
    }
    __syncthreads();
    {
        const int blk = tid >> 4, c = tid & 15;
        const int base = 256*blk + 16*c;
        float2 x[16], y[16];
        #pragma unroll
        for (int d = 0; d < 16; ++d) x[d] = bufB[phys(base + d)];
        dft16<1>(x, y);
        #pragma unroll
        for (int p0 = 0; p0 < 16; ++p0) bufB[phys(base + p0)] = y[p0];
    }
    __syncthreads();
    {
        const int blk = tid >> 4, p0 = tid & 15;
        const int base = 256*blk + p0;
        float2 x[16], y[16];
        #pragma unroll
        for (int c = 0; c < 16; ++c) x[c] = bufB[phys(base + 16*c)];
        twiddle_apply(x, PI2 * (float)p0 / 256.f);
        dft16<1>(x, y);
        #pragma unroll
        for (int p1 = 0; p1 < 16; ++p1) bufB[phys(base + 16*p1)] = y[p1];
    }
    __syncthreads();
    {
        const int qq = tid;
        float2 x[16], y[16];
        #pragma unroll
        for (int t = 0; t < 16; ++t) x[t] = bufB[phys(qq + 256*t)];
        twiddle_apply(x, PI2 * (float)qq / 4096.f);
        dft16<1>(x, y);
        const float scale = 0.125f / 4096.f;
        #pragma unroll
        for (int p2 = 0; p2 < 16; ++p2)
            orow[qq + 256*p2] = y[p2].x * scale;
    }
}

// ---------------------------------------------------------------------------
// Transpose + split (UNCHANGED, validated r4-r6)
// ---------------------------------------------------------------------------
__global__ __launch_bounds__(256) void transpose_split_kernel(
    const float* __restrict__ ot, ushort* __restrict__ oth,
    ushort* __restrict__ otl)
{
    __shared__ float tile[64][65];
    const int tid = threadIdx.x;
    const int m0  = blockIdx.x * 64;
    const int n0  = blockIdx.y * 64;
    const int r   = tid >> 4;
    const int c   = tid & 15;

    #pragma unroll
    for (int rr = 0; rr < 4; ++rr) {
        const int nl = r + rr * 16;
        float4 v = *(const float4*)(ot + (size_t)(n0 + nl) * M_TOTAL + m0 + c * 4);
        tile[nl][c * 4 + 0] = v.x; tile[nl][c * 4 + 1] = v.y;
        tile[nl][c * 4 + 2] = v.z; tile[nl][c * 4 + 3] = v.w;
    }
    __syncthreads();
    #pragma unroll
    for (int rr = 0; rr < 4; ++rr) {
        const int ml = r + rr * 16;
        ushort4 h, l;
        split1(tile[c * 4 + 0][ml], h.x, l.x);
        split1(tile[c * 4 + 1][ml], h.y, l.y);
        split1(tile[c * 4 + 2][ml], h.z, l.z);
        split1(tile[c * 4 + 3][ml], h.w, l.w);
        *(ushort4*)(oth + (size_t)(m0 + ml) * HIDDEN + n0 + c * 4) = h;
        *(ushort4*)(otl + (size_t)(m0 + ml) * HIDDEN + n0 + c * 4) = l;
    }
}

// ---------------------------------------------------------------------------
// Output GEMM (MFMA): out[m][n] = ot^T[m][:] . Wo[n][:] + bo[n]
// 128x128, 4 waves, BK=32, double-buffered (64 KiB), new swizzle.
// A (oth/otl) is always bf16 -> gload16; B per PS.
// ---------------------------------------------------------------------------
template<int PS>
__device__ __forceinline__ void out2_stage(
    int tid, int k0,
    const ushort* __restrict__ oth, const ushort* __restrict__ otl,
    const float* __restrict__ Wo,
    const ushort* __restrict__ woh, const ushort* __restrict__ wol,
    int m0, int n0,
    ushort* __restrict__ Ah, ushort* __restrict__ Al,
    ushort* __restrict__ Bh, ushort* __restrict__ Bl)
{
    #pragma unroll
    for (int t = 0; t < 2; ++t) {
        const int s   = tid + t * 256;      // slot [0,512)
        const int row = s >> 2;             // [0,128)
        const int ch  = s & 3;
        const int fsw = (row >> 1) & 3;
        {   // A: ot^T rows m (bf16 planes)
            const size_t g = (size_t)(m0 + row) * HIDDEN + k0 + (size_t)(ch ^ fsw) * 8;
#if HAVE_GLL
            gload16(oth + g, Ah + (size_t)s * 8);
            gload16(otl + g, Al + (size_t)s * 8);
#else
            *(s16x8*)(Ah + (size_t)s * 8) = *(const s16x8*)(oth + g);
            *(s16x8*)(Al + (size_t)s * 8) = *(const s16x8*)(otl + g);
#endif
        }
        if constexpr (PS >= 1) {
            const size_t g = (size_t)(n0 + row) * HIDDEN + k0 + (size_t)(ch ^ fsw) * 8;
#if HAVE_GLL
            gload16(woh + g, Bh + (size_t)s * 8);
            gload16(wol + g, Bl + (size_t)s * 8);
#else
            *(s16x8*)(Bh + (size_t)s * 8) = *(const s16x8*)(woh + g);
            *(s16x8*)(Bl + (size_t)s * 8) = *(const s16x8*)(wol + g);
#endif
        } else {
            const int cs = (ch ^ fsw) * 8;
            const float* g = Wo + (size_t)(n0 + row) * HIDDEN + k0 + ch * 8;
            split8_store(g, Bh + row * 32 + cs, Bl + row * 32 + cs);
        }
    }
}

template<int PS>
__global__ __launch_bounds__(256) void gemm_out_mfma2(
    const ushort* __restrict__ oth, const ushort* __restrict__ otl,
    const float* __restrict__ Wo,
    const ushort* __restrict__ woh, const ushort* __restrict__ wol,
    const float* __restrict__ bo, float* __restrict__ out)
{
    __shared__ ushort Ah[2][128][32], Al[2][128][32];
    __shared__ ushort Bh[2][128][32], Bl[2][128][32];

    const int tid  = threadIdx.x;
    const int lane = tid & 63;
    const int w    = tid >> 6;
    const int m0   = blockIdx.x * 128;
    const int n0   = blockIdx.y * 128;

    const int fr = lane & 15;
    const int fc = lane >> 4;
    const int cc = (fc ^ ((fr >> 1) & 3)) * 8;

    f32x4 acc[2][8];
    #pragma unroll
    for (int i = 0; i < 2; ++i)
        #pragma unroll
        for (int j = 0; j < 8; ++j)
            acc[i][j] = (f32x4){0.f, 0.f, 0.f, 0.f};

    out2_stage<PS>(tid, 0, oth, otl, Wo, woh, wol, m0, n0,
                   &Ah[0][0][0], &Al[0][0][0], &Bh[0][0][0], &Bl[0][0][0]);
    __syncthreads();

    for (int ks = 0; ks < HIDDEN / 32; ++ks) {
        const int cur = ks & 1;
        if (ks + 1 < HIDDEN / 32) {
            const int nxt = cur ^ 1;
            out2_stage<PS>(tid, (ks + 1) * 32, oth, otl, Wo, woh, wol, m0, n0,
                           &Ah[nxt][0][0], &Al[nxt][0][0], &Bh[nxt][0][0], &Bl[nxt][0][0]);
        }
        {
            const ushort* pAh = &Ah[cur][0][0];
            const ushort* pAl = &Al[cur][0][0];
            const ushort* pBh = &Bh[cur][0][0];
            const ushort* pBl = &Bl[cur][0][0];
            s16x8 a_h[2], a_l[2];
            #pragma unroll
            for (int i = 0; i < 2; ++i) {
                const int R = w * 32 + i * 16 + fr;
                a_h[i] = *(const s16x8*)(pAh + R * 32 + cc);
                a_l[i] = *(const s16x8*)(pAl + R * 32 + cc);
            }
            #pragma unroll
            for (int j = 0; j < 8; ++j) {
                const int R = j * 16 + fr;
                const s16x8 b_h = *(const s16x8*)(pBh + R * 32 + cc);
                const s16x8 b_l = *(const s16x8*)(pBl + R * 32 + cc);
                #pragma unroll
                for (int i = 0; i < 2; ++i) {
                    acc[i][j] = __builtin_amdgcn_mfma_f32_16x16x32_bf16(a_h[i], b_h, acc[i][j], 0, 0, 0);
                    acc[i][j] = __builtin_amdgcn_mfma_f32_16x16x32_bf16(a_h[i], b_l, acc[i][j], 0, 0, 0);
                    acc[i][j] = __builtin_amdgcn_mfma_f32_16x16x32_bf16(a_l[i], b_h, acc[i][j], 0, 0, 0);
                }
            }
        }
        __syncthreads();
    }

    const int rq = lane >> 4;
    float bo_v[8];
    #pragma unroll
    for (int j = 0; j < 8; ++j) bo_v[j] = bo[n0 + j * 16 + fr];
    #pragma unroll
    for (int i = 0; i < 2; ++i) {
        #pragma unroll
        for (int r = 0; r < 4; ++r) {
            const int m = m0 + w * 32 + i * 16 + rq * 4 + r;
            float* dst = out + (size_t)m * HIDDEN + n0;
            #pragma unroll
            for (int j = 0; j < 8; ++j)
                dst[j * 16 + fr] = acc[i][j][r] + bo_v[j];
        }
    }
}

// ---------------------------------------------------------------------------
extern "C" void kernel_launch(void* const* d_in, const int* in_sizes, int n_in,
                              void* d_out, int out_size, void* d_ws, size_t ws_size,
                              hipStream_t stream)
{
    const float* x  = (const float*)d_in[0];
    const float* Wq = (const float*)d_in[1];
    const float* bq = (const float*)d_in[2];
    const float* Wk = (const float*)d_in[3];
    const float* bk = (const float*)d_in[4];
    const float* Wv = (const float*)d_in[5];
    const float* bv = (const float*)d_in[6];
    const float* Wo = (const float*)d_in[7];
    const float* bo = (const float*)d_in[8];
    float* out = (float*)d_out;

    const size_t plane = (size_t)HIDDEN * M_TOTAL;   // 16.7M elements
    char* base = (char*)d_ws;
    float* qt = (float*)base;
    float* kt = qt + plane;
    float* vt = kt + plane;
    float* ot = qt;                    // FFT output aliases q plane
    ushort* oth = (ushort*)kt;         // transposed bf16 hi plane (dead k plane)
    ushort* otl = (ushort*)vt;         // lo plane (dead v plane)

    // optional pre-split region after the 3 fp32 planes
    ushort* wqh = (ushort*)(base + plane * 12);  // stacked [3072][1024] hi
    ushort* wql = wqh + 3 * WSZ;                 // stacked lo
    ushort* woh = wql + 3 * WSZ;
    ushort* wol = woh + WSZ;
    ushort* xh  = wol + WSZ;
    ushort* xl  = xh + plane;

    const size_t need_W    = plane * 12 + WSZ * 2 * 8;          // ~218.1 MB
    const size_t need_full = need_W + plane * 2 * 2;            // ~285.2 MB
    const int PS = (ws_size >= need_full) ? 2 : (ws_size >= need_W ? 1 : 0);

    if (PS >= 1) {
        split_kernel<<<(unsigned)(WSZ / 2048), 256, 0, stream>>>(Wq, wqh, wql);
        split_kernel<<<(unsigned)(WSZ / 2048), 256, 0, stream>>>(Wk, wqh + WSZ, wql + WSZ);
        split_kernel<<<(unsigned)(WSZ / 2048), 256, 0, stream>>>(Wv, wqh + 2 * WSZ, wql + 2 * WSZ);
        split_kernel<<<(unsigned)(WSZ / 2048), 256, 0, stream>>>(Wo, woh, wol);
    }
    if (PS == 2)
        split_kernel<<<(unsigned)(plane / 2048), 256, 0, stream>>>(x, xh, xl);

    const dim3 gq(M_TOTAL / 256, 12);
    if (PS == 2)
        gemm_qkv_mfma2<2><<<gq, 512, 0, stream>>>(x, xh, xl, Wq, Wk, Wv, wqh, wql, bq, bk, bv, qt);
    else if (PS == 1)
        gemm_qkv_mfma2<1><<<gq, 512, 0, stream>>>(x, xh, xl, Wq, Wk, Wv, wqh, wql, bq, bk, bv, qt);
    else
        gemm_qkv_mfma2<0><<<gq, 512, 0, stream>>>(x, xh, xl, Wq, Wk, Wv, wqh, wql, bq, bk, bv, qt);

    fft_attn_kernel<<<dim3(HIDDEN * BATCH), 256, 0, stream>>>(qt, kt, vt, ot);

    transpose_split_kernel<<<dim3(M_TOTAL / 64, HIDDEN / 64), 256, 0, stream>>>(
        ot, oth, otl);

    const dim3 go(M_TOTAL / 128, HIDDEN / 128);
    if (PS >= 1)
        gemm_out_mfma2<1><<<go, 256, 0, stream>>>(oth, otl, Wo, woh, wol, bo, out);
    else
        gemm_out_mfma2<0><<<go, 256, 0, stream>>>(oth, otl, Wo, woh, wol, bo, out);
}

// Round 8
// 526.049 us; speedup vs baseline: 1.1402x; 1.0765x over previous
//
#include <hip/hip_runtime.h>
#include <hip/hip_bf16.h>
#include <math.h>

#define HIDDEN   1024
#define HEADS    16
#define HEAD_DIM 64
#define BATCH    4
#define SEQ      4096
#define M_TOTAL  (BATCH * SEQ)          // 16384
#define FFT_N    4096
#define PI2      6.28318530717958647692f

typedef short  s16x8 __attribute__((ext_vector_type(8)));   // 8 bf16 = 4 VGPR (MFMA A/B frag)
typedef float  f32x4 __attribute__((ext_vector_type(4)));   // MFMA C/D frag

#if defined(__has_builtin)
#if __has_builtin(__builtin_amdgcn_global_load_lds)
#define HAVE_GLL 1
#else
#define HAVE_GLL 0
#endif
#else
#define HAVE_GLL 0
#endif

#if HAVE_GLL
// async global->LDS, 16B/lane. dest = wave-uniform base + lane*16 (linear in slot).
__device__ __forceinline__ void gload16(const void* g, void* l) {
    __builtin_amdgcn_global_load_lds(
        (const __attribute__((address_space(1))) unsigned int*)g,
        (__attribute__((address_space(3))) unsigned int*)l,
        16, 0, 0);
}
#endif

// RNE bf16 bits
__device__ __forceinline__ ushort bf16_rne(float f) {
    union { __hip_bfloat16 b; ushort u; } cv;
    cv.b = __float2bfloat16(f);
    return cv.u;
}

// RNE split from registers: v = hi + lo
__device__ __forceinline__ void split8_regs(float4 v0, float4 v1,
                                            ushort* __restrict__ hd,
                                            ushort* __restrict__ ld) {
    const float vv[8] = {v0.x, v0.y, v0.z, v0.w, v1.x, v1.y, v1.z, v1.w};
    s16x8 hv, lv;
    #pragma unroll
    for (int e = 0; e < 8; ++e) {
        const ushort h = bf16_rne(vv[e]);
        const float hf = __uint_as_float((unsigned)h << 16);
        hv[e] = (short)h;
        lv[e] = (short)bf16_rne(vv[e] - hf);
    }
    *(s16x8*)hd = hv;
    *(s16x8*)ld = lv;
}

// truncation split (transpose_split, validated r4-r7)
__device__ __forceinline__ void split1(float v, ushort& h, ushort& l) {
    unsigned u = __float_as_uint(v);
    h = (ushort)(u >> 16);
    float hif = __uint_as_float(u & 0xffff0000u);
    float lof = v - hif;
    l = (ushort)(__float_as_uint(lof) >> 16);
}

// ---------------------------------------------------------------------------
// QKV GEMM (MFMA): stacked-W [3072][1024] x x^T -> ct[p][n][m]
// 256x256 tile, 512 thr / 8 waves (4m x 2n), BK=32, dbuf 128 KiB.
// T14 schedule: ISSUE fp32 loads(k+1) -> COMPUTE(k) -> split+ds_write(k+1)
// -> barrier. Load latency hides under the 96-MFMA compute phase.
// Swizzle (validated r7, 0 conflicts): elem-col = (ch ^ ((row>>1)&3))*8.
// ---------------------------------------------------------------------------
__global__ __launch_bounds__(512, 2) void gemm_qkv_mfma3(
    const float* __restrict__ x,
    const float* __restrict__ Wq, const float* __restrict__ Wk,
    const float* __restrict__ Wv,
    const float* __restrict__ bq, const float* __restrict__ bk,
    const float* __restrict__ bv,
    float* __restrict__ qkvt)
{
    __shared__ ushort Ah[2][256 * 32], Al[2][256 * 32];
    __shared__ ushort Bh[2][256 * 32], Bl[2][256 * 32];   // 128 KiB total

    const int tid  = threadIdx.x;
    const int lane = tid & 63;
    const int wid  = tid >> 6;
    const int wm   = wid & 3;
    const int wn   = wid >> 2;
    const int m0   = blockIdx.x * 256;
    const int ng0  = blockIdx.y * 256;
    const int p    = ng0 >> 10;
    const int n0p  = ng0 & 1023;

    const float* __restrict__ Wsel = (p == 0) ? Wq : (p == 1 ? Wk : Wv);
    const float* __restrict__ bias = (p == 0) ? bq : (p == 1 ? bk : bv);
    float* __restrict__ ct = qkvt + (size_t)p * HIDDEN * M_TOTAL;

    // staging slot constants (2 slots/thread)
    int srow[2], sch[2], soff[2];
    #pragma unroll
    for (int t = 0; t < 2; ++t) {
        const int s = tid + t * 512;
        srow[t] = s >> 2;
        sch[t]  = s & 3;
        soff[t] = srow[t] * 32 + ((sch[t] ^ ((srow[t] >> 1) & 3)) * 8);
    }

    const int fr = lane & 15;
    const int fc = lane >> 4;
    const int cc = (fc ^ ((fr >> 1) & 3)) * 8;

    f32x4 acc[8][4];
    #pragma unroll
    for (int nf = 0; nf < 8; ++nf)
        #pragma unroll
        for (int mf = 0; mf < 4; ++mf)
            acc[nf][mf] = (f32x4){0.f, 0.f, 0.f, 0.f};

    float4 la0[2], la1[2], lb0[2], lb1[2];   // in-flight registers

    #define QKV_ISSUE(K0)                                                      \
        _Pragma("unroll")                                                      \
        for (int t = 0; t < 2; ++t) {                                          \
            const float* ga = Wsel + (size_t)(n0p + srow[t]) * HIDDEN + (K0) + sch[t] * 8; \
            const float* gb = x    + (size_t)(m0  + srow[t]) * HIDDEN + (K0) + sch[t] * 8; \
            la0[t] = *(const float4*)ga;  la1[t] = *(const float4*)(ga + 4);   \
            lb0[t] = *(const float4*)gb;  lb1[t] = *(const float4*)(gb + 4);   \
        }

    #define QKV_WRITE(BUF)                                                     \
        _Pragma("unroll")                                                      \
        for (int t = 0; t < 2; ++t) {                                          \
            split8_regs(la0[t], la1[t], &Ah[BUF][soff[t]], &Al[BUF][soff[t]]); \
            split8_regs(lb0[t], lb1[t], &Bh[BUF][soff[t]], &Bl[BUF][soff[t]]); \
        }

    QKV_ISSUE(0);
    QKV_WRITE(0);
    __syncthreads();

    for (int ks = 0; ks < HIDDEN / 32; ++ks) {
        const int cur = ks & 1;
        if (ks + 1 < HIDDEN / 32) { QKV_ISSUE((ks + 1) * 32); }

        {   // ---- compute(cur): 96 MFMA
            const ushort* pAh = Ah[cur];
            const ushort* pAl = Al[cur];
            const ushort* pBh = Bh[cur];
            const ushort* pBl = Bl[cur];
            s16x8 b_h[4], b_l[4];
            #pragma unroll
            for (int mf = 0; mf < 4; ++mf) {
                const int R = wm * 64 + mf * 16 + fr;
                b_h[mf] = *(const s16x8*)(pBh + R * 32 + cc);
                b_l[mf] = *(const s16x8*)(pBl + R * 32 + cc);
            }
            __builtin_amdgcn_s_setprio(1);
            #pragma unroll
            for (int nf = 0; nf < 8; ++nf) {
                const int R = wn * 128 + nf * 16 + fr;
                const s16x8 a_h = *(const s16x8*)(pAh + R * 32 + cc);
                const s16x8 a_l = *(const s16x8*)(pAl + R * 32 + cc);
                #pragma unroll
                for (int mf = 0; mf < 4; ++mf) {
                    acc[nf][mf] = __builtin_amdgcn_mfma_f32_16x16x32_bf16(a_h, b_h[mf], acc[nf][mf], 0, 0, 0);
                    acc[nf][mf] = __builtin_amdgcn_mfma_f32_16x16x32_bf16(a_h, b_l[mf], acc[nf][mf], 0, 0, 0);
                    acc[nf][mf] = __builtin_amdgcn_mfma_f32_16x16x32_bf16(a_l, b_h[mf], acc[nf][mf], 0, 0, 0);
                }
            }
            __builtin_amdgcn_s_setprio(0);
        }

        if (ks + 1 < HIDDEN / 32) { QKV_WRITE(cur ^ 1); }
        __syncthreads();
    }
    #undef QKV_ISSUE
    #undef QKV_WRITE

    // epilogue (validated r7): D row n_local = wn*128+nf*16+rq*4+r; col m = wm*64+mf*16+fr
    const int rq = lane >> 4;
    #pragma unroll
    for (int nf = 0; nf < 8; ++nf) {
        #pragma unroll
        for (int r = 0; r < 4; ++r) {
            const int nl = wn * 128 + nf * 16 + rq * 4 + r;
            const float bv = bias[n0p + nl];
            float* dst = ct + (size_t)(n0p + nl) * M_TOTAL + m0 + wm * 64;
            #pragma unroll
            for (int mf = 0; mf < 4; ++mf)
                dst[mf * 16 + fr] = acc[nf][mf][r] + bv;
        }
    }
}

// ---------------------------------------------------------------------------
// Radix-16 FFT machinery (UNCHANGED, validated r5-r7)
// ---------------------------------------------------------------------------
__device__ __forceinline__ float2 cmul(float2 a, float2 b) {
    return {a.x*b.x - a.y*b.y, a.x*b.y + a.y*b.x};
}

__device__ __forceinline__ int phys(int p) { return p ^ ((p >> 4) & 15); }

template<int DIR>
__device__ __forceinline__ void dft16(const float2* x, float2* X) {
    float2 t[16];
    #pragma unroll
    for (int n0 = 0; n0 < 4; ++n0) {
        float2 a = x[n0], b = x[n0+4], c = x[n0+8], d = x[n0+12];
        float2 s0 = {a.x+c.x, a.y+c.y}, s1 = {a.x-c.x, a.y-c.y};
        float2 s2 = {b.x+d.x, b.y+d.y}, s3 = {b.x-d.x, b.y-d.y};
        t[n0*4+0] = {s0.x+s2.x, s0.y+s2.y};
        t[n0*4+2] = {s0.x-s2.x, s0.y-s2.y};
        if (DIR < 0) {
            t[n0*4+1] = {s1.x+s3.y, s1.y-s3.x};
            t[n0*4+3] = {s1.x-s3.y, s1.y+s3.x};
        } else {
            t[n0*4+1] = {s1.x-s3.y, s1.y+s3.x};
            t[n0*4+3] = {s1.x+s3.y, s1.y-s3.x};
        }
    }
    const float C1 = 0.92387953251128674f;
    const float S1_ = 0.38268343236508978f;
    const float R2 = 0.70710678118654752f;
    #define TW(idx, cc_, ss_) t[idx] = cmul(t[idx], (float2){cc_, DIR*(ss_)})
    TW(1*4+1, C1, S1_);   TW(1*4+2, R2, R2);    TW(1*4+3, S1_, C1);
    TW(2*4+1, R2, R2);    TW(2*4+2, 0.f, 1.f);  TW(2*4+3, -R2, R2);
    TW(3*4+1, S1_, C1);   TW(3*4+2, -R2, R2);   TW(3*4+3, -C1, -S1_);
    #undef TW
    #pragma unroll
    for (int k0 = 0; k0 < 4; ++k0) {
        float2 a = t[0+k0], b = t[4+k0], c = t[8+k0], d = t[12+k0];
        float2 s0 = {a.x+c.x, a.y+c.y}, s1 = {a.x-c.x, a.y-c.y};
        float2 s2 = {b.x+d.x, b.y+d.y}, s3 = {b.x-d.x, b.y-d.y};
        X[k0+0]  = {s0.x+s2.x, s0.y+s2.y};
        X[k0+8]  = {s0.x-s2.x, s0.y-s2.y};
        if (DIR < 0) {
            X[k0+4]  = {s1.x+s3.y, s1.y-s3.x};
            X[k0+12] = {s1.x-s3.y, s1.y+s3.x};
        } else {
            X[k0+4]  = {s1.x-s3.y, s1.y+s3.x};
            X[k0+12] = {s1.x+s3.y, s1.y-s3.x};
        }
    }
}

__device__ __forceinline__ void twiddle_apply(float2* y, float ang) {
    float s, c;
    __sincosf(ang, &s, &c);
    const float2 base = {c, s};
    float2 w = base;
    #pragma unroll
    for (int u = 1; u < 16; ++u) {
        y[u] = cmul(y[u], w);
        w = cmul(w, base);
    }
}

__global__ __launch_bounds__(256) void fft_attn_kernel(
    const float* __restrict__ qt, const float* __restrict__ kt,
    const float* __restrict__ vt, float* __restrict__ ot)
{
    __shared__ float2 bufA[FFT_N];
    __shared__ float2 bufB[FFT_N];

    const int tid = threadIdx.x;
    const int bid = blockIdx.x;
    const int n   = bid >> 2;
    const int b   = bid & 3;

    const size_t off = (size_t)n * M_TOTAL + (size_t)b * SEQ;
    const float* qrow = qt + off;
    const float* krow = kt + off;
    const float* vrow = vt + off;
    float*       orow = ot + off;

    {
        const int q = tid;
        float2 xA[16], xB[16], yA[16], yB[16];
        #pragma unroll
        for (int r = 0; r < 16; ++r) {
            xA[r] = { qrow[q + 256*r], krow[q + 256*r] };
            xB[r] = { vrow[q + 256*r], 0.f };
        }
        dft16<-1>(xA, yA);
        dft16<-1>(xB, yB);
        const float ang = -PI2 * (float)q / 4096.f;
        twiddle_apply(yA, ang);
        twiddle_apply(yB, ang);
        #pragma unroll
        for (int u = 0; u < 16; ++u) {
            bufA[phys(q + 256*u)] = yA[u];
            bufB[phys(q + 256*u)] = yB[u];
        }
    }
    __syncthreads();
    {
        const int blk = tid >> 4, a = tid & 15;
        const int base = 256*blk + a;
        float2 xA[16], xB[16], yA[16], yB[16];
        #pragma unroll
        for (int c = 0; c < 16; ++c) {
            xA[c] = bufA[phys(base + 16*c)];
            xB[c] = bufB[phys(base + 16*c)];
        }
        dft16<-1>(xA, yA);
        dft16<-1>(xB, yB);
        const float ang = -PI2 * (float)a / 256.f;
        twiddle_apply(yA, ang);
        twiddle_apply(yB, ang);
        #pragma unroll
        for (int c = 0; c < 16; ++c) {
            bufA[phys(base + 16*c)] = yA[c];
            bufB[phys(base + 16*c)] = yB[c];
        }
    }
    __syncthreads();
    {
        const int blk = tid >> 4, c = tid & 15;
        const int base = 256*blk + 16*c;
        float2 xA[16], xB[16], yA[16], yB[16];
        #pragma unroll
        for (int a2 = 0; a2 < 16; ++a2) {
            xA[a2] = bufA[phys(base + a2)];
            xB[a2] = bufB[phys(base + a2)];
        }
        dft16<-1>(xA, yA);
        dft16<-1>(xB, yB);
        #pragma unroll
        for (int d = 0; d < 16; ++d) {
            bufA[phys(base + d)] = yA[d];
            bufB[phys(base + d)] = yB[d];
        }
    }
    __syncthreads();
    #pragma unroll
    for (int it = 0; it < 16; ++it) {
        const int p  = tid + it * 256;
        const int j  = ((p & 15) << 8) | (p & 0xF0) | (p >> 8);
        const int jn = (FFT_N - j) & (FFT_N - 1);
        const int pn = ((jn & 15) << 8) | (jn & 0xF0) | (jn >> 8);
        const float2 Zj = bufA[phys(p)];
        const float2 Zn = bufA[phys(pn)];
        const float2 Q = { 0.5f*(Zj.x + Zn.x), 0.5f*(Zj.y - Zn.y) };
        const float2 K = { 0.5f*(Zj.y + Zn.y), -0.5f*(Zj.x - Zn.x) };
        const float2 G = { Q.x*K.x + Q.y*K.y, Q.y*K.x - Q.x*K.y };
        const float2 V = bufB[phys(p)];
        bufB[phys(p)] = { G.x*V.x - G.y*V.y, G.x*V.y + G.y*V.x };
    }
    __syncthreads();
    {
        const int blk = tid >> 4, c = tid & 15;
        const int base = 256*blk + 16*c;
        float2 x[16], y[16];
        #pragma unroll
        for (int d = 0; d < 16; ++d) x[d] = bufB[phys(base + d)];
        dft16<1>(x, y);
        #pragma unroll
        for (int p0 = 0; p0 < 16; ++p0) bufB[phys(base + p0)] = y[p0];
    }
    __syncthreads();
    {
        const int blk = tid >> 4, p0 = tid & 15;
        const int base = 256*blk + p0;
        float2 x[16], y[16];
        #pragma unroll
        for (int c = 0; c < 16; ++c) x[c] = bufB[phys(base + 16*c)];
        twiddle_apply(x, PI2 * (float)p0 / 256.f);
        dft16<1>(x, y);
        #pragma unroll
        for (int p1 = 0; p1 < 16; ++p1) bufB[phys(base + 16*p1)] = y[p1];
    }
    __syncthreads();
    {
        const int qq = tid;
        float2 x[16], y[16];
        #pragma unroll
        for (int t = 0; t < 16; ++t) x[t] = bufB[phys(qq + 256*t)];
        twiddle_apply(x, PI2 * (float)qq / 4096.f);
        dft16<1>(x, y);
        const float scale = 0.125f / 4096.f;
        #pragma unroll
        for (int p2 = 0; p2 < 16; ++p2)
            orow[qq + 256*p2] = y[p2].x * scale;
    }
}

// ---------------------------------------------------------------------------
// Transpose + split (UNCHANGED, validated r4-r7)
// ---------------------------------------------------------------------------
__global__ __launch_bounds__(256) void transpose_split_kernel(
    const float* __restrict__ ot, ushort* __restrict__ oth,
    ushort* __restrict__ otl)
{
    __shared__ float tile[64][65];
    const int tid = threadIdx.x;
    const int m0  = blockIdx.x * 64;
    const int n0  = blockIdx.y * 64;
    const int r   = tid >> 4;
    const int c   = tid & 15;

    #pragma unroll
    for (int rr = 0; rr < 4; ++rr) {
        const int nl = r + rr * 16;
        float4 v = *(const float4*)(ot + (size_t)(n0 + nl) * M_TOTAL + m0 + c * 4);
        tile[nl][c * 4 + 0] = v.x; tile[nl][c * 4 + 1] = v.y;
        tile[nl][c * 4 + 2] = v.z; tile[nl][c * 4 + 3] = v.w;
    }
    __syncthreads();
    #pragma unroll
    for (int rr = 0; rr < 4; ++rr) {
        const int ml = r + rr * 16;
        ushort4 h, l;
        split1(tile[c * 4 + 0][ml], h.x, l.x);
        split1(tile[c * 4 + 1][ml], h.y, l.y);
        split1(tile[c * 4 + 2][ml], h.z, l.z);
        split1(tile[c * 4 + 3][ml], h.w, l.w);
        *(ushort4*)(oth + (size_t)(m0 + ml) * HIDDEN + n0 + c * 4) = h;
        *(ushort4*)(otl + (size_t)(m0 + ml) * HIDDEN + n0 + c * 4) = l;
    }
}

// ---------------------------------------------------------------------------
// Output GEMM (MFMA): out[m][n] = ot^T[m][:].Wo[n][:] + bo[n]
// 128x128 tile, 4 waves, BK=32, dbuf 64 KiB (2 blocks/CU).
// A (oth/otl bf16): gload16 pure copy (linear dest + pre-swizzled source).
// B (Wo fp32): T14 reg-stage, split+write after compute.
// ---------------------------------------------------------------------------
__global__ __launch_bounds__(256, 2) void gemm_out_mfma3(
    const ushort* __restrict__ oth, const ushort* __restrict__ otl,
    const float* __restrict__ Wo, const float* __restrict__ bo,
    float* __restrict__ out)
{
    __shared__ ushort Ah[2][128 * 32], Al[2][128 * 32];
    __shared__ ushort Bh[2][128 * 32], Bl[2][128 * 32];   // 64 KiB

    const int tid  = threadIdx.x;
    const int lane = tid & 63;
    const int w    = tid >> 6;
    const int m0   = blockIdx.x * 128;
    const int n0   = blockIdx.y * 128;

    int srow[2], sch[2], soff[2], schS[2];
    #pragma unroll
    for (int t = 0; t < 2; ++t) {
        const int s = tid + t * 256;
        srow[t] = s >> 2;
        sch[t]  = s & 3;
        schS[t] = sch[t] ^ ((srow[t] >> 1) & 3);
        soff[t] = srow[t] * 32 + schS[t] * 8;   // also the linear slot*8 for gload
    }

    const int fr = lane & 15;
    const int fc = lane >> 4;
    const int cc = (fc ^ ((fr >> 1) & 3)) * 8;

    f32x4 acc[2][8];
    #pragma unroll
    for (int i = 0; i < 2; ++i)
        #pragma unroll
        for (int j = 0; j < 8; ++j)
            acc[i][j] = (f32x4){0.f, 0.f, 0.f, 0.f};

    float4 lb0[2], lb1[2];

    // A staging: gload16 with PRE-SWIZZLED SOURCE chunk, LINEAR dest (slot s*16B)
    #define OUT_ISSUE(K0, BUF)                                                  \
        _Pragma("unroll")                                                       \
        for (int t = 0; t < 2; ++t) {                                           \
            const size_t ga = (size_t)(m0 + srow[t]) * HIDDEN + (K0) + (size_t)schS[t] * 8; \
            const int s = tid + t * 256;                                        \
            OUT_A_COPY(BUF, s, ga);                                             \
            const float* gb = Wo + (size_t)(n0 + srow[t]) * HIDDEN + (K0) + sch[t] * 8; \
            lb0[t] = *(const float4*)gb;  lb1[t] = *(const float4*)(gb + 4);    \
        }

#if HAVE_GLL
    #define OUT_A_COPY(BUF, S, GA)                                              \
        gload16(oth + (GA), &Ah[BUF][(size_t)(S) * 8]);                         \
        gload16(otl + (GA), &Al[BUF][(size_t)(S) * 8]);
#else
    #define OUT_A_COPY(BUF, S, GA)                                              \
        *(s16x8*)&Ah[BUF][(size_t)(S) * 8] = *(const s16x8*)(oth + (GA));       \
        *(s16x8*)&Al[BUF][(size_t)(S) * 8] = *(const s16x8*)(otl + (GA));
#endif

    #define OUT_WRITE(BUF)                                                      \
        _Pragma("unroll")                                                       \
        for (int t = 0; t < 2; ++t)                                             \
            split8_regs(lb0[t], lb1[t], &Bh[BUF][soff[t]], &Bl[BUF][soff[t]]);

    OUT_ISSUE(0, 0);
    OUT_WRITE(0);
    __syncthreads();

    for (int ks = 0; ks < HIDDEN / 32; ++ks) {
        const int cur = ks & 1;
        if (ks + 1 < HIDDEN / 32) { OUT_ISSUE((ks + 1) * 32, cur ^ 1); }

        {
            const ushort* pAh = Ah[cur];
            const ushort* pAl = Al[cur];
            const ushort* pBh = Bh[cur];
            const ushort* pBl = Bl[cur];
            s16x8 a_h[2], a_l[2];
            #pragma unroll
            for (int i = 0; i < 2; ++i) {
                const int R = w * 32 + i * 16 + fr;
                a_h[i] = *(const s16x8*)(pAh + R * 32 + cc);
                a_l[i] = *(const s16x8*)(pAl + R * 32 + cc);
            }
            __builtin_amdgcn_s_setprio(1);
            #pragma unroll
            for (int j = 0; j < 8; ++j) {
                const int R = j * 16 + fr;
                const s16x8 b_h = *(const s16x8*)(pBh + R * 32 + cc);
                const s16x8 b_l = *(const s16x8*)(pBl + R * 32 + cc);
                #pragma unroll
                for (int i = 0; i < 2; ++i) {
                    acc[i][j] = __builtin_amdgcn_mfma_f32_16x16x32_bf16(a_h[i], b_h, acc[i][j], 0, 0, 0);
                    acc[i][j] = __builtin_amdgcn_mfma_f32_16x16x32_bf16(a_h[i], b_l, acc[i][j], 0, 0, 0);
                    acc[i][j] = __builtin_amdgcn_mfma_f32_16x16x32_bf16(a_l[i], b_h, acc[i][j], 0, 0, 0);
                }
            }
            __builtin_amdgcn_s_setprio(0);
        }

        if (ks + 1 < HIDDEN / 32) { OUT_WRITE(cur ^ 1); }
        __syncthreads();
    }
    #undef OUT_ISSUE
    #undef OUT_A_COPY
    #undef OUT_WRITE

    const int rq = lane >> 4;
    float bo_v[8];
    #pragma unroll
    for (int j = 0; j < 8; ++j) bo_v[j] = bo[n0 + j * 16 + fr];
    #pragma unroll
    for (int i = 0; i < 2; ++i) {
        #pragma unroll
        for (int r = 0; r < 4; ++r) {
            const int m = m0 + w * 32 + i * 16 + rq * 4 + r;
            float* dst = out + (size_t)m * HIDDEN + n0;
            #pragma unroll
            for (int j = 0; j < 8; ++j)
                dst[j * 16 + fr] = acc[i][j][r] + bo_v[j];
        }
    }
}

// ---------------------------------------------------------------------------
extern "C" void kernel_launch(void* const* d_in, const int* in_sizes, int n_in,
                              void* d_out, int out_size, void* d_ws, size_t ws_size,
                              hipStream_t stream)
{
    const float* x  = (const float*)d_in[0];
    const float* Wq = (const float*)d_in[1];
    const float* bq = (const float*)d_in[2];
    const float* Wk = (const float*)d_in[3];
    const float* bk = (const float*)d_in[4];
    const float* Wv = (const float*)d_in[5];
    const float* bv = (const float*)d_in[6];
    const float* Wo = (const float*)d_in[7];
    const float* bo = (const float*)d_in[8];
    float* out = (float*)d_out;

    const size_t plane = (size_t)HIDDEN * M_TOTAL;   // 16.7M elements
    float* qt = (float*)d_ws;
    float* kt = qt + plane;
    float* vt = kt + plane;
    float* ot = qt;                    // FFT output aliases q plane
    ushort* oth = (ushort*)kt;         // transposed bf16 hi plane (dead k plane)
    ushort* otl = (ushort*)vt;         // lo plane (dead v plane)

    gemm_qkv_mfma3<<<dim3(M_TOTAL / 256, 12), 512, 0, stream>>>(
        x, Wq, Wk, Wv, bq, bk, bv, qt);

    fft_attn_kernel<<<dim3(HIDDEN * BATCH), 256, 0, stream>>>(qt, kt, vt, ot);

    transpose_split_kernel<<<dim3(M_TOTAL / 64, HIDDEN / 64), 256, 0, stream>>>(
        ot, oth, otl);

    gemm_out_mfma3<<<dim3(M_TOTAL / 128, HIDDEN / 128), 256, 0, stream>>>(
        oth, otl, Wo, bo, out);
}

// Round 9
// 502.724 us; speedup vs baseline: 1.1931x; 1.0464x over previous
//
#include <hip/hip_runtime.h>
#include <hip/hip_bf16.h>
#include <math.h>

#define HIDDEN   1024
#define HEADS    16
#define HEAD_DIM 64
#define BATCH    4
#define SEQ      4096
#define M_TOTAL  (BATCH * SEQ)          // 16384
#define FFT_N    4096
#define PI2      6.28318530717958647692f

typedef short  s16x8 __attribute__((ext_vector_type(8)));   // 8 bf16 = 4 VGPR (MFMA A/B frag)
typedef float  f32x4 __attribute__((ext_vector_type(4)));   // MFMA C/D frag

#if defined(__has_builtin)
#if __has_builtin(__builtin_amdgcn_global_load_lds)
#define HAVE_GLL 1
#else
#define HAVE_GLL 0
#endif
#else
#define HAVE_GLL 0
#endif

#if HAVE_GLL
// async global->LDS, 16B/lane. dest = wave-uniform base + lane*16 (linear in slot).
__device__ __forceinline__ void gload16(const void* g, void* l) {
    __builtin_amdgcn_global_load_lds(
        (const __attribute__((address_space(1))) unsigned int*)g,
        (__attribute__((address_space(3))) unsigned int*)l,
        16, 0, 0);
}
#endif

// RNE bf16 bits
__device__ __forceinline__ ushort bf16_rne(float f) {
    union { __hip_bfloat16 b; ushort u; } cv;
    cv.b = __float2bfloat16(f);
    return cv.u;
}

// RNE split from registers: v = hi + lo
__device__ __forceinline__ void split8_regs(float4 v0, float4 v1,
                                            ushort* __restrict__ hd,
                                            ushort* __restrict__ ld) {
    const float vv[8] = {v0.x, v0.y, v0.z, v0.w, v1.x, v1.y, v1.z, v1.w};
    s16x8 hv, lv;
    #pragma unroll
    for (int e = 0; e < 8; ++e) {
        const ushort h = bf16_rne(vv[e]);
        const float hf = __uint_as_float((unsigned)h << 16);
        hv[e] = (short)h;
        lv[e] = (short)bf16_rne(vv[e] - hf);
    }
    *(s16x8*)hd = hv;
    *(s16x8*)ld = lv;
}

// truncation split (transpose_split, validated r4-r8)
__device__ __forceinline__ void split1(float v, ushort& h, ushort& l) {
    unsigned u = __float_as_uint(v);
    h = (ushort)(u >> 16);
    float hif = __uint_as_float(u & 0xffff0000u);
    float lof = v - hif;
    l = (ushort)(__float_as_uint(lof) >> 16);
}

// ---------------------------------------------------------------------------
// QKV GEMM (MFMA): stacked-W [3072][1024] x x^T -> ct[p][n][m]
// 256x256 tile, 1024 thr / 16 waves (4r x 4c), wave tile 64n x 64m.
// BK=32, dbuf 128 KiB (1 block/CU, 4 waves/SIMD -- occupancy fix vs r8's 2).
// r7-validated schedule: STAGE(k+1) -> COMPUTE(k) -> barrier.
// Swizzle (validated r7/r8, 0 conflicts): elem-col = (ch ^ ((row>>1)&3))*8.
// acc 64 AGPR/wave (was 128) -> ~175 unified regs/wave -> 4 waves/SIMD.
// ---------------------------------------------------------------------------
__global__ __launch_bounds__(1024, 1) void gemm_qkv_mfma4(
    const float* __restrict__ x,
    const float* __restrict__ Wq, const float* __restrict__ Wk,
    const float* __restrict__ Wv,
    const float* __restrict__ bq, const float* __restrict__ bk,
    const float* __restrict__ bv,
    float* __restrict__ qkvt)
{
    __shared__ ushort Ah[2][8192], Al[2][8192];   // W tile  [256n][32k] hi/lo
    __shared__ ushort Bh[2][8192], Bl[2][8192];   // x tile  [256m][32k] hi/lo (128 KiB)

    const int tid  = threadIdx.x;
    const int lane = tid & 63;
    const int wid  = tid >> 6;        // 0..15
    const int wr   = wid >> 2;        // n-dim wave 0..3
    const int wc   = wid & 3;         // m-dim wave 0..3
    const int m0   = blockIdx.x * 256;
    const int ng0  = blockIdx.y * 256;            // stacked n in [0,3072)
    const int p    = ng0 >> 10;
    const int n0p  = ng0 & 1023;

    const float* __restrict__ Wsel = (p == 0) ? Wq : (p == 1 ? Wk : Wv);
    const float* __restrict__ bias = (p == 0) ? bq : (p == 1 ? bk : bv);
    float* __restrict__ ct = qkvt + (size_t)p * HIDDEN * M_TOTAL;

    // one staging slot per thread: row = tid>>2 in [0,256), ch = tid&3
    const int row  = tid >> 2;
    const int ch   = tid & 3;
    const int soff = row * 32 + ((ch ^ ((row >> 1) & 3)) * 8);

    const int fr = lane & 15;
    const int fc = lane >> 4;
    const int cc = (fc ^ ((fr >> 1) & 3)) * 8;

    f32x4 acc[4][4];
    #pragma unroll
    for (int rf = 0; rf < 4; ++rf)
        #pragma unroll
        for (int cf = 0; cf < 4; ++cf)
            acc[rf][cf] = (f32x4){0.f, 0.f, 0.f, 0.f};

    #define QKV_STAGE(K0, BUF) {                                               \
        const float* ga = Wsel + (size_t)(n0p + row) * HIDDEN + (K0) + ch * 8; \
        const float* gb = x    + (size_t)(m0  + row) * HIDDEN + (K0) + ch * 8; \
        float4 a0 = *(const float4*)ga, a1 = *(const float4*)(ga + 4);         \
        float4 b0 = *(const float4*)gb, b1 = *(const float4*)(gb + 4);         \
        split8_regs(a0, a1, &Ah[BUF][soff], &Al[BUF][soff]);                   \
        split8_regs(b0, b1, &Bh[BUF][soff], &Bl[BUF][soff]);                   \
    }

    QKV_STAGE(0, 0);
    __syncthreads();

    for (int ks = 0; ks < HIDDEN / 32; ++ks) {
        const int cur = ks & 1;
        if (ks + 1 < HIDDEN / 32) { QKV_STAGE((ks + 1) * 32, cur ^ 1); }

        {   // compute(cur): 48 MFMA / wave
            const ushort* pAh = Ah[cur];
            const ushort* pAl = Al[cur];
            const ushort* pBh = Bh[cur];
            const ushort* pBl = Bl[cur];
            s16x8 b_h[4], b_l[4];
            #pragma unroll
            for (int cf = 0; cf < 4; ++cf) {
                const int R = wc * 64 + cf * 16 + fr;
                b_h[cf] = *(const s16x8*)(pBh + R * 32 + cc);
                b_l[cf] = *(const s16x8*)(pBl + R * 32 + cc);
            }
            #pragma unroll
            for (int rf = 0; rf < 4; ++rf) {
                const int R = wr * 64 + rf * 16 + fr;
                const s16x8 a_h = *(const s16x8*)(pAh + R * 32 + cc);
                const s16x8 a_l = *(const s16x8*)(pAl + R * 32 + cc);
                #pragma unroll
                for (int cf = 0; cf < 4; ++cf) {
                    acc[rf][cf] = __builtin_amdgcn_mfma_f32_16x16x32_bf16(a_h, b_h[cf], acc[rf][cf], 0, 0, 0);
                    acc[rf][cf] = __builtin_amdgcn_mfma_f32_16x16x32_bf16(a_h, b_l[cf], acc[rf][cf], 0, 0, 0);
                    acc[rf][cf] = __builtin_amdgcn_mfma_f32_16x16x32_bf16(a_l, b_h[cf], acc[rf][cf], 0, 0, 0);
                }
            }
        }
        __syncthreads();
    }
    #undef QKV_STAGE

    // epilogue (r7-validated mapping, 64-stride waves):
    // D row n_local = wr*64 + rf*16 + rq*4 + r ; col m_local = wc*64 + cf*16 + fr
    const int rq = lane >> 4;
    #pragma unroll
    for (int rf = 0; rf < 4; ++rf) {
        #pragma unroll
        for (int r = 0; r < 4; ++r) {
            const int nl = wr * 64 + rf * 16 + rq * 4 + r;
            const float bv = bias[n0p + nl];
            float* dst = ct + (size_t)(n0p + nl) * M_TOTAL + m0 + wc * 64;
            #pragma unroll
            for (int cf = 0; cf < 4; ++cf)
                dst[cf * 16 + fr] = acc[rf][cf][r] + bv;
        }
    }
}

// ---------------------------------------------------------------------------
// Radix-16 FFT machinery (UNCHANGED, validated r5-r8)
// ---------------------------------------------------------------------------
__device__ __forceinline__ float2 cmul(float2 a, float2 b) {
    return {a.x*b.x - a.y*b.y, a.x*b.y + a.y*b.x};
}

__device__ __forceinline__ int phys(int p) { return p ^ ((p >> 4) & 15); }

template<int DIR>
__device__ __forceinline__ void dft16(const float2* x, float2* X) {
    float2 t[16];
    #pragma unroll
    for (int n0 = 0; n0 < 4; ++n0) {
        float2 a = x[n0], b = x[n0+4], c = x[n0+8], d = x[n0+12];
        float2 s0 = {a.x+c.x, a.y+c.y}, s1 = {a.x-c.x, a.y-c.y};
        float2 s2 = {b.x+d.x, b.y+d.y}, s3 = {b.x-d.x, b.y-d.y};
        t[n0*4+0] = {s0.x+s2.x, s0.y+s2.y};
        t[n0*4+2] = {s0.x-s2.x, s0.y-s2.y};
        if (DIR < 0) {
            t[n0*4+1] = {s1.x+s3.y, s1.y-s3.x};
            t[n0*4+3] = {s1.x-s3.y, s1.y+s3.x};
        } else {
            t[n0*4+1] = {s1.x-s3.y, s1.y+s3.x};
            t[n0*4+3] = {s1.x+s3.y, s1.y-s3.x};
        }
    }
    const float C1 = 0.92387953251128674f;
    const float S1_ = 0.38268343236508978f;
    const float R2 = 0.70710678118654752f;
    #define TW(idx, cc_, ss_) t[idx] = cmul(t[idx], (float2){cc_, DIR*(ss_)})
    TW(1*4+1, C1, S1_);   TW(1*4+2, R2, R2);    TW(1*4+3, S1_, C1);
    TW(2*4+1, R2, R2);    TW(2*4+2, 0.f, 1.f);  TW(2*4+3, -R2, R2);
    TW(3*4+1, S1_, C1);   TW(3*4+2, -R2, R2);   TW(3*4+3, -C1, -S1_);
    #undef TW
    #pragma unroll
    for (int k0 = 0; k0 < 4; ++k0) {
        float2 a = t[0+k0], b = t[4+k0], c = t[8+k0], d = t[12+k0];
        float2 s0 = {a.x+c.x, a.y+c.y}, s1 = {a.x-c.x, a.y-c.y};
        float2 s2 = {b.x+d.x, b.y+d.y}, s3 = {b.x-d.x, b.y-d.y};
        X[k0+0]  = {s0.x+s2.x, s0.y+s2.y};
        X[k0+8]  = {s0.x-s2.x, s0.y-s2.y};
        if (DIR < 0) {
            X[k0+4]  = {s1.x+s3.y, s1.y-s3.x};
            X[k0+12] = {s1.x-s3.y, s1.y+s3.x};
        } else {
            X[k0+4]  = {s1.x-s3.y, s1.y+s3.x};
            X[k0+12] = {s1.x+s3.y, s1.y-s3.x};
        }
    }
}

__device__ __forceinline__ void twiddle_apply(float2* y, float ang) {
    float s, c;
    __sincosf(ang, &s, &c);
    const float2 base = {c, s};
    float2 w = base;
    #pragma unroll
    for (int u = 1; u < 16; ++u) {
        y[u] = cmul(y[u], w);
        w = cmul(w, base);
    }
}

__global__ __launch_bounds__(256) void fft_attn_kernel(
    const float* __restrict__ qt, const float* __restrict__ kt,
    const float* __restrict__ vt, float* __restrict__ ot)
{
    __shared__ float2 bufA[FFT_N];
    __shared__ float2 bufB[FFT_N];

    const int tid = threadIdx.x;
    const int bid = blockIdx.x;
    const int n   = bid >> 2;
    const int b   = bid & 3;

    const size_t off = (size_t)n * M_TOTAL + (size_t)b * SEQ;
    const float* qrow = qt + off;
    const float* krow = kt + off;
    const float* vrow = vt + off;
    float*       orow = ot + off;

    {
        const int q = tid;
        float2 xA[16], xB[16], yA[16], yB[16];
        #pragma unroll
        for (int r = 0; r < 16; ++r) {
            xA[r] = { qrow[q + 256*r], krow[q + 256*r] };
            xB[r] = { vrow[q + 256*r], 0.f };
        }
        dft16<-1>(xA, yA);
        dft16<-1>(xB, yB);
        const float ang = -PI2 * (float)q / 4096.f;
        twiddle_apply(yA, ang);
        twiddle_apply(yB, ang);
        #pragma unroll
        for (int u = 0; u < 16; ++u) {
            bufA[phys(q + 256*u)] = yA[u];
            bufB[phys(q + 256*u)] = yB[u];
        }
    }
    __syncthreads();
    {
        const int blk = tid >> 4, a = tid & 15;
        const int base = 256*blk + a;
        float2 xA[16], xB[16], yA[16], yB[16];
        #pragma unroll
        for (int c = 0; c < 16; ++c) {
            xA[c] = bufA[phys(base + 16*c)];
            xB[c] = bufB[phys(base + 16*c)];
        }
        dft16<-1>(xA, yA);
        dft16<-1>(xB, yB);
        const float ang = -PI2 * (float)a / 256.f;
        twiddle_apply(yA, ang);
        twiddle_apply(yB, ang);
        #pragma unroll
        for (int c = 0; c < 16; ++c) {
            bufA[phys(base + 16*c)] = yA[c];
            bufB[phys(base + 16*c)] = yB[c];
        }
    }
    __syncthreads();
    {
        const int blk = tid >> 4, c = tid & 15;
        const int base = 256*blk + 16*c;
        float2 xA[16], xB[16], yA[16], yB[16];
        #pragma unroll
        for (int a2 = 0; a2 < 16; ++a2) {
            xA[a2] = bufA[phys(base + a2)];
            xB[a2] = bufB[phys(base + a2)];
        }
        dft16<-1>(xA, yA);
        dft16<-1>(xB, yB);
        #pragma unroll
        for (int d = 0; d < 16; ++d) {
            bufA[phys(base + d)] = yA[d];
            bufB[phys(base + d)] = yB[d];
        }
    }
    __syncthreads();
    #pragma unroll
    for (int it = 0; it < 16; ++it) {
        const int p  = tid + it * 256;
        const int j  = ((p & 15) << 8) | (p & 0xF0) | (p >> 8);
        const int jn = (FFT_N - j) & (FFT_N - 1);
        const int pn = ((jn & 15) << 8) | (jn & 0xF0) | (jn >> 8);
        const float2 Zj = bufA[phys(p)];
        const float2 Zn = bufA[phys(pn)];
        const float2 Q = { 0.5f*(Zj.x + Zn.x), 0.5f*(Zj.y - Zn.y) };
        const float2 K = { 0.5f*(Zj.y + Zn.y), -0.5f*(Zj.x - Zn.x) };
        const float2 G = { Q.x*K.x + Q.y*K.y, Q.y*K.x - Q.x*K.y };
        const float2 V = bufB[phys(p)];
        bufB[phys(p)] = { G.x*V.x - G.y*V.y, G.x*V.y + G.y*V.x };
    }
    __syncthreads();
    {
        const int blk = tid >> 4, c = tid & 15;
        const int base = 256*blk + 16*c;
        float2 x[16], y[16];
        #pragma unroll
        for (int d = 0; d < 16; ++d) x[d] = bufB[phys(base + d)];
        dft16<1>(x, y);
        #pragma unroll
        for (int p0 = 0; p0 < 16; ++p0) bufB[phys(base + p0)] = y[p0];
    }
    __syncthreads();
    {
        const int blk = tid >> 4, p0 = tid & 15;
        const int base = 256*blk + p0;
        float2 x[16], y[16];
        #pragma unroll
        for (int c = 0; c < 16; ++c) x[c] = bufB[phys(base + 16*c)];
        twiddle_apply(x, PI2 * (float)p0 / 256.f);
        dft16<1>(x, y);
        #pragma unroll
        for (int p1 = 0; p1 < 16; ++p1) bufB[phys(base + 16*p1)] = y[p1];
    }
    __syncthreads();
    {
        const int qq = tid;
        float2 x[16], y[16];
        #pragma unroll
        for (int t = 0; t < 16; ++t) x[t] = bufB[phys(qq + 256*t)];
        twiddle_apply(x, PI2 * (float)qq / 4096.f);
        dft16<1>(x, y);
        const float scale = 0.125f / 4096.f;
        #pragma unroll
        for (int p2 = 0; p2 < 16; ++p2)
            orow[qq + 256*p2] = y[p2].x * scale;
    }
}

// ---------------------------------------------------------------------------
// Transpose + split (UNCHANGED, validated r4-r8)
// ---------------------------------------------------------------------------
__global__ __launch_bounds__(256) void transpose_split_kernel(
    const float* __restrict__ ot, ushort* __restrict__ oth,
    ushort* __restrict__ otl)
{
    __shared__ float tile[64][65];
    const int tid = threadIdx.x;
    const int m0  = blockIdx.x * 64;
    const int n0  = blockIdx.y * 64;
    const int r   = tid >> 4;
    const int c   = tid & 15;

    #pragma unroll
    for (int rr = 0; rr < 4; ++rr) {
        const int nl = r + rr * 16;
        float4 v = *(const float4*)(ot + (size_t)(n0 + nl) * M_TOTAL + m0 + c * 4);
        tile[nl][c * 4 + 0] = v.x; tile[nl][c * 4 + 1] = v.y;
        tile[nl][c * 4 + 2] = v.z; tile[nl][c * 4 + 3] = v.w;
    }
    __syncthreads();
    #pragma unroll
    for (int rr = 0; rr < 4; ++rr) {
        const int ml = r + rr * 16;
        ushort4 h, l;
        split1(tile[c * 4 + 0][ml], h.x, l.x);
        split1(tile[c * 4 + 1][ml], h.y, l.y);
        split1(tile[c * 4 + 2][ml], h.z, l.z);
        split1(tile[c * 4 + 3][ml], h.w, l.w);
        *(ushort4*)(oth + (size_t)(m0 + ml) * HIDDEN + n0 + c * 4) = h;
        *(ushort4*)(otl + (size_t)(m0 + ml) * HIDDEN + n0 + c * 4) = l;
    }
}

// ---------------------------------------------------------------------------
// Output GEMM (MFMA): out[m][n] = ot^T[m][:].Wo[n][:] + bo[n]
// Same 1024-thread / 16-wave / 256x256 structure as qkv.
// A (oth/otl bf16): gload16, linear dest + pre-swizzled source (validated r8).
// B (Wo fp32): in-kernel RNE split.
// ---------------------------------------------------------------------------
__global__ __launch_bounds__(1024, 1) void gemm_out_mfma4(
    const ushort* __restrict__ oth, const ushort* __restrict__ otl,
    const float* __restrict__ Wo, const float* __restrict__ bo,
    float* __restrict__ out)
{
    __shared__ ushort Ah[2][8192], Al[2][8192];   // ot^T tile [256m][32k]
    __shared__ ushort Bh[2][8192], Bl[2][8192];   // Wo  tile [256n][32k]

    const int tid  = threadIdx.x;
    const int lane = tid & 63;
    const int wid  = tid >> 6;
    const int wr   = wid >> 2;        // m-dim wave
    const int wc   = wid & 3;         // n-dim wave
    const int m0   = blockIdx.x * 256;
    const int n0   = blockIdx.y * 256;

    const int row  = tid >> 2;
    const int ch   = tid & 3;
    const int chS  = ch ^ ((row >> 1) & 3);
    const int soff = row * 32 + chS * 8;   // swizzled write col; == linear slot*8 for gload

    const int fr = lane & 15;
    const int fc = lane >> 4;
    const int cc = (fc ^ ((fr >> 1) & 3)) * 8;

    f32x4 acc[4][4];
    #pragma unroll
    for (int rf = 0; rf < 4; ++rf)
        #pragma unroll
        for (int cf = 0; cf < 4; ++cf)
            acc[rf][cf] = (f32x4){0.f, 0.f, 0.f, 0.f};

#if HAVE_GLL
    #define OUT_A_COPY(BUF, GA)                                        \
        gload16(oth + (GA), &Ah[BUF][(size_t)tid * 8]);                \
        gload16(otl + (GA), &Al[BUF][(size_t)tid * 8]);
#else
    #define OUT_A_COPY(BUF, GA)                                        \
        *(s16x8*)&Ah[BUF][(size_t)tid * 8] = *(const s16x8*)(oth + (GA)); \
        *(s16x8*)&Al[BUF][(size_t)tid * 8] = *(const s16x8*)(otl + (GA));
#endif

    #define OUT_STAGE(K0, BUF) {                                               \
        const size_t ga = (size_t)(m0 + row) * HIDDEN + (K0) + (size_t)chS * 8;\
        OUT_A_COPY(BUF, ga);                                                   \
        const float* gb = Wo + (size_t)(n0 + row) * HIDDEN + (K0) + ch * 8;    \
        float4 b0 = *(const float4*)gb, b1 = *(const float4*)(gb + 4);         \
        split8_regs(b0, b1, &Bh[BUF][soff], &Bl[BUF][soff]);                   \
    }

    OUT_STAGE(0, 0);
    __syncthreads();

    for (int ks = 0; ks < HIDDEN / 32; ++ks) {
        const int cur = ks & 1;
        if (ks + 1 < HIDDEN / 32) { OUT_STAGE((ks + 1) * 32, cur ^ 1); }

        {
            const ushort* pAh = Ah[cur];
            const ushort* pAl = Al[cur];
            const ushort* pBh = Bh[cur];
            const ushort* pBl = Bl[cur];
            s16x8 b_h[4], b_l[4];
            #pragma unroll
            for (int cf = 0; cf < 4; ++cf) {
                const int R = wc * 64 + cf * 16 + fr;
                b_h[cf] = *(const s16x8*)(pBh + R * 32 + cc);
                b_l[cf] = *(const s16x8*)(pBl + R * 32 + cc);
            }
            #pragma unroll
            for (int rf = 0; rf < 4; ++rf) {
                const int R = wr * 64 + rf * 16 + fr;
                const s16x8 a_h = *(const s16x8*)(pAh + R * 32 + cc);
                const s16x8 a_l = *(const s16x8*)(pAl + R * 32 + cc);
                #pragma unroll
                for (int cf = 0; cf < 4; ++cf) {
                    acc[rf][cf] = __builtin_amdgcn_mfma_f32_16x16x32_bf16(a_h, b_h[cf], acc[rf][cf], 0, 0, 0);
                    acc[rf][cf] = __builtin_amdgcn_mfma_f32_16x16x32_bf16(a_h, b_l[cf], acc[rf][cf], 0, 0, 0);
                    acc[rf][cf] = __builtin_amdgcn_mfma_f32_16x16x32_bf16(a_l, b_h[cf], acc[rf][cf], 0, 0, 0);
                }
            }
        }
        __syncthreads();
    }
    #undef OUT_STAGE
    #undef OUT_A_COPY

    // epilogue: D row m_local = wr*64 + rf*16 + rq*4 + r ; col n_local = wc*64 + cf*16 + fr
    const int rq = lane >> 4;
    float bo_v[4];
    #pragma unroll
    for (int cf = 0; cf < 4; ++cf) bo_v[cf] = bo[n0 + wc * 64 + cf * 16 + fr];
    #pragma unroll
    for (int rf = 0; rf < 4; ++rf) {
        #pragma unroll
        for (int r = 0; r < 4; ++r) {
            const int ml = wr * 64 + rf * 16 + rq * 4 + r;
            float* dst = out + (size_t)(m0 + ml) * HIDDEN + n0 + wc * 64;
            #pragma unroll
            for (int cf = 0; cf < 4; ++cf)
                dst[cf * 16 + fr] = acc[rf][cf][r] + bo_v[cf];
        }
    }
}

// ---------------------------------------------------------------------------
extern "C" void kernel_launch(void* const* d_in, const int* in_sizes, int n_in,
                              void* d_out, int out_size, void* d_ws, size_t ws_size,
                              hipStream_t stream)
{
    const float* x  = (const float*)d_in[0];
    const float* Wq = (const float*)d_in[1];
    const float* bq = (const float*)d_in[2];
    const float* Wk = (const float*)d_in[3];
    const float* bk = (const float*)d_in[4];
    const float* Wv = (const float*)d_in[5];
    const float* bv = (const float*)d_in[6];
    const float* Wo = (const float*)d_in[7];
    const float* bo = (const float*)d_in[8];
    float* out = (float*)d_out;

    const size_t plane = (size_t)HIDDEN * M_TOTAL;   // 16.7M elements
    float* qt = (float*)d_ws;
    float* kt = qt + plane;
    float* vt = kt + plane;
    float* ot = qt;                    // FFT output aliases q plane
    ushort* oth = (ushort*)kt;         // transposed bf16 hi plane (dead k plane)
    ushort* otl = (ushort*)vt;         // lo plane (dead v plane)

    gemm_qkv_mfma4<<<dim3(M_TOTAL / 256, 12), 1024, 0, stream>>>(
        x, Wq, Wk, Wv, bq, bk, bv, qt);

    fft_attn_kernel<<<dim3(HIDDEN * BATCH), 256, 0, stream>>>(qt, kt, vt, ot);

    transpose_split_kernel<<<dim3(M_TOTAL / 64, HIDDEN / 64), 256, 0, stream>>>(
        ot, oth, otl);

    gemm_out_mfma4<<<dim3(M_TOTAL / 256, HIDDEN / 256), 1024, 0, stream>>>(
        oth, otl, Wo, bo, out);
}

// Round 11
// 425.321 us; speedup vs baseline: 1.4102x; 1.1820x over previous
//
#include <hip/hip_runtime.h>
#include <hip/hip_bf16.h>
#include <math.h>

#define HIDDEN   1024
#define HEADS    16
#define HEAD_DIM 64
#define BATCH    4
#define SEQ      4096
#define M_TOTAL  (BATCH * SEQ)          // 16384
#define FFT_N    4096
#define PI2      6.28318530717958647692f

typedef _Float16 f16x8 __attribute__((ext_vector_type(8)));   // 8 fp16 = 4 VGPR (MFMA A/B frag)
typedef float    f32x4 __attribute__((ext_vector_type(4)));   // MFMA C/D frag

#if defined(__has_builtin)
#if __has_builtin(__builtin_amdgcn_global_load_lds)
#define HAVE_GLL 1
#else
#define HAVE_GLL 0
#endif
#else
#define HAVE_GLL 0
#endif

#if HAVE_GLL
// async global->LDS, 16B/lane. dest = wave-uniform base + lane*16 (linear in slot).
__device__ __forceinline__ void gload16(const void* g, void* l) {
    __builtin_amdgcn_global_load_lds(
        (const __attribute__((address_space(1))) unsigned int*)g,
        (__attribute__((address_space(3))) unsigned int*)l,
        16, 0, 0);
}
#endif

// fp16 one-sided split: v = hi + lo + O(2^-22 |v|)
__device__ __forceinline__ void split8_f16(float4 v0, float4 v1,
                                           ushort* __restrict__ hd,
                                           ushort* __restrict__ ld) {
    const float vv[8] = {v0.x, v0.y, v0.z, v0.w, v1.x, v1.y, v1.z, v1.w};
    f16x8 hv, lv;
    #pragma unroll
    for (int e = 0; e < 8; ++e) {
        const _Float16 h = (_Float16)vv[e];
        hv[e] = h;
        lv[e] = (_Float16)(vv[e] - (float)h);
    }
    *(f16x8*)hd = hv;
    *(f16x8*)ld = lv;
}

// fp16 single round: 8 floats -> 8 fp16
__device__ __forceinline__ void cvt8_f16(float4 v0, float4 v1,
                                         ushort* __restrict__ d) {
    const float vv[8] = {v0.x, v0.y, v0.z, v0.w, v1.x, v1.y, v1.z, v1.w};
    f16x8 hv;
    #pragma unroll
    for (int e = 0; e < 8; ++e) hv[e] = (_Float16)vv[e];
    *(f16x8*)d = hv;
}

// scalar fp16 split (transpose kernel)
__device__ __forceinline__ void split1_f16(float v, ushort& h, ushort& l) {
    const _Float16 hh = (_Float16)v;
    const _Float16 ll = (_Float16)(v - (float)hh);
    union { _Float16 f; ushort u; } ch, cl;
    ch.f = hh; cl.f = ll;
    h = ch.u; l = cl.u;
}

// ---------------------------------------------------------------------------
// QKV GEMM (MFMA fp16): stacked-W [3072][1024] x x^T -> ct[p][n][m]
// 256x256 tile, 1024 thr / 16 waves (4r x 4c), wave tile 64n x 64m, BK=32.
// 2-product one-sided split: ct = Wh.x16 + Wl.x16  (x rounded to fp16).
// Product-major MFMA order: all 16 cells product-1, then product-2 ->
// acc reuse distance 16, no latency stalls (fix for r7-r9's 3-chain).
// LDS 96 KiB dbuf; r9-validated single-barrier schedule + swizzle.
// ---------------------------------------------------------------------------
__global__ __launch_bounds__(1024, 1) void gemm_qkv_mfma5(
    const float* __restrict__ x,
    const float* __restrict__ Wq, const float* __restrict__ Wk,
    const float* __restrict__ Wv,
    const float* __restrict__ bq, const float* __restrict__ bk,
    const float* __restrict__ bv,
    float* __restrict__ qkvt)
{
    __shared__ ushort Ah[2][8192], Al[2][8192];   // W tile [256n][32k] hi/lo fp16
    __shared__ ushort Bh[2][8192];                // x tile [256m][32k] fp16 (96 KiB)

    const int tid  = threadIdx.x;
    const int lane = tid & 63;
    const int wid  = tid >> 6;        // 0..15
    const int wr   = wid >> 2;        // n-dim wave 0..3
    const int wc   = wid & 3;         // m-dim wave 0..3
    const int m0   = blockIdx.x * 256;
    const int ng0  = blockIdx.y * 256;            // stacked n in [0,3072)
    const int p    = ng0 >> 10;
    const int n0p  = ng0 & 1023;

    const float* __restrict__ Wsel = (p == 0) ? Wq : (p == 1 ? Wk : Wv);
    const float* __restrict__ bias = (p == 0) ? bq : (p == 1 ? bk : bv);
    float* __restrict__ ct = qkvt + (size_t)p * HIDDEN * M_TOTAL;

    const int row  = tid >> 2;        // [0,256)
    const int ch   = tid & 3;
    const int soff = row * 32 + ((ch ^ ((row >> 1) & 3)) * 8);

    const int fr = lane & 15;
    const int fc = lane >> 4;
    const int cc = (fc ^ ((fr >> 1) & 3)) * 8;

    f32x4 acc[4][4];
    #pragma unroll
    for (int rf = 0; rf < 4; ++rf)
        #pragma unroll
        for (int cf = 0; cf < 4; ++cf)
            acc[rf][cf] = (f32x4){0.f, 0.f, 0.f, 0.f};

    #define QKV_STAGE(K0, BUF) {                                               \
        const float* ga = Wsel + (size_t)(n0p + row) * HIDDEN + (K0) + ch * 8; \
        const float* gb = x    + (size_t)(m0  + row) * HIDDEN + (K0) + ch * 8; \
        float4 a0 = *(const float4*)ga, a1 = *(const float4*)(ga + 4);         \
        float4 b0 = *(const float4*)gb, b1 = *(const float4*)(gb + 4);         \
        split8_f16(a0, a1, &Ah[BUF][soff], &Al[BUF][soff]);                    \
        cvt8_f16(b0, b1, &Bh[BUF][soff]);                                      \
    }

    QKV_STAGE(0, 0);
    __syncthreads();

    for (int ks = 0; ks < HIDDEN / 32; ++ks) {
        const int cur = ks & 1;
        if (ks + 1 < HIDDEN / 32) { QKV_STAGE((ks + 1) * 32, cur ^ 1); }

        {   // compute(cur): 32 MFMA / wave, product-major
            const ushort* pAh = Ah[cur];
            const ushort* pAl = Al[cur];
            const ushort* pBh = Bh[cur];
            f16x8 a_h[4], a_l[4], b_h[4];
            #pragma unroll
            for (int rf = 0; rf < 4; ++rf) {
                const int R = wr * 64 + rf * 16 + fr;
                a_h[rf] = *(const f16x8*)(pAh + R * 32 + cc);
                a_l[rf] = *(const f16x8*)(pAl + R * 32 + cc);
            }
            #pragma unroll
            for (int cf = 0; cf < 4; ++cf) {
                const int R = wc * 64 + cf * 16 + fr;
                b_h[cf] = *(const f16x8*)(pBh + R * 32 + cc);
            }
            #pragma unroll
            for (int rf = 0; rf < 4; ++rf)
                #pragma unroll
                for (int cf = 0; cf < 4; ++cf)
                    acc[rf][cf] = __builtin_amdgcn_mfma_f32_16x16x32_f16(a_h[rf], b_h[cf], acc[rf][cf], 0, 0, 0);
            #pragma unroll
            for (int rf = 0; rf < 4; ++rf)
                #pragma unroll
                for (int cf = 0; cf < 4; ++cf)
                    acc[rf][cf] = __builtin_amdgcn_mfma_f32_16x16x32_f16(a_l[rf], b_h[cf], acc[rf][cf], 0, 0, 0);
        }
        __syncthreads();
    }
    #undef QKV_STAGE

    // epilogue (r7/r9-validated): D row n_local = wr*64+rf*16+rq*4+r ; col m = wc*64+cf*16+fr
    const int rq = lane >> 4;
    #pragma unroll
    for (int rf = 0; rf < 4; ++rf) {
        #pragma unroll
        for (int r = 0; r < 4; ++r) {
            const int nl = wr * 64 + rf * 16 + rq * 4 + r;
            const float bv = bias[n0p + nl];
            float* dst = ct + (size_t)(n0p + nl) * M_TOTAL + m0 + wc * 64;
            #pragma unroll
            for (int cf = 0; cf < 4; ++cf)
                dst[cf * 16 + fr] = acc[rf][cf][r] + bv;
        }
    }
}

// ---------------------------------------------------------------------------
// Radix-16 FFT machinery (UNCHANGED, validated r5-r9)
// ---------------------------------------------------------------------------
__device__ __forceinline__ float2 cmul(float2 a, float2 b) {
    return {a.x*b.x - a.y*b.y, a.x*b.y + a.y*b.x};
}

__device__ __forceinline__ int phys(int p) { return p ^ ((p >> 4) & 15); }

template<int DIR>
__device__ __forceinline__ void dft16(const float2* x, float2* X) {
    float2 t[16];
    #pragma unroll
    for (int n0 = 0; n0 < 4; ++n0) {
        float2 a = x[n0], b = x[n0+4], c = x[n0+8], d = x[n0+12];
        float2 s0 = {a.x+c.x, a.y+c.y}, s1 = {a.x-c.x, a.y-c.y};
        float2 s2 = {b.x+d.x, b.y+d.y}, s3 = {b.x-d.x, b.y-d.y};
        t[n0*4+0] = {s0.x+s2.x, s0.y+s2.y};
        t[n0*4+2] = {s0.x-s2.x, s0.y-s2.y};
        if (DIR < 0) {
            t[n0*4+1] = {s1.x+s3.y, s1.y-s3.x};
            t[n0*4+3] = {s1.x-s3.y, s1.y+s3.x};
        } else {
            t[n0*4+1] = {s1.x-s3.y, s1.y+s3.x};
            t[n0*4+3] = {s1.x+s3.y, s1.y-s3.x};
        }
    }
    const float C1 = 0.92387953251128674f;
    const float S1_ = 0.38268343236508978f;
    const float R2 = 0.70710678118654752f;
    #define TW(idx, cc_, ss_) t[idx] = cmul(t[idx], (float2){cc_, DIR*(ss_)})
    TW(1*4+1, C1, S1_);   TW(1*4+2, R2, R2);    TW(1*4+3, S1_, C1);
    TW(2*4+1, R2, R2);    TW(2*4+2, 0.f, 1.f);  TW(2*4+3, -R2, R2);
    TW(3*4+1, S1_, C1);   TW(3*4+2, -R2, R2);   TW(3*4+3, -C1, -S1_);
    #undef TW
    #pragma unroll
    for (int k0 = 0; k0 < 4; ++k0) {
        float2 a = t[0+k0], b = t[4+k0], c = t[8+k0], d = t[12+k0];
        float2 s0 = {a.x+c.x, a.y+c.y}, s1 = {a.x-c.x, a.y-c.y};
        float2 s2 = {b.x+d.x, b.y+d.y}, s3 = {b.x-d.x, b.y-d.y};
        X[k0+0]  = {s0.x+s2.x, s0.y+s2.y};
        X[k0+8]  = {s0.x-s2.x, s0.y-s2.y};
        if (DIR < 0) {
            X[k0+4]  = {s1.x+s3.y, s1.y-s3.x};
            X[k0+12] = {s1.x-s3.y, s1.y+s3.x};
        } else {
            X[k0+4]  = {s1.x-s3.y, s1.y+s3.x};
            X[k0+12] = {s1.x+s3.y, s1.y-s3.x};
        }
    }
}

__device__ __forceinline__ void twiddle_apply(float2* y, float ang) {
    float s, c;
    __sincosf(ang, &s, &c);
    const float2 base = {c, s};
    float2 w = base;
    #pragma unroll
    for (int u = 1; u < 16; ++u) {
        y[u] = cmul(y[u], w);
        w = cmul(w, base);
    }
}

__global__ __launch_bounds__(256) void fft_attn_kernel(
    const float* __restrict__ qt, const float* __restrict__ kt,
    const float* __restrict__ vt, float* __restrict__ ot)
{
    __shared__ float2 bufA[FFT_N];
    __shared__ float2 bufB[FFT_N];

    const int tid = threadIdx.x;
    const int bid = blockIdx.x;
    const int n   = bid >> 2;
    const int b   = bid & 3;

    const size_t off = (size_t)n * M_TOTAL + (size_t)b * SEQ;
    const float* qrow = qt + off;
    const float* krow = kt + off;
    const float* vrow = vt + off;
    float*       orow = ot + off;

    {
        const int q = tid;
        float2 xA[16], xB[16], yA[16], yB[16];
        #pragma unroll
        for (int r = 0; r < 16; ++r) {
            xA[r] = { qrow[q + 256*r], krow[q + 256*r] };
            xB[r] = { vrow[q + 256*r], 0.f };
        }
        dft16<-1>(xA, yA);
        dft16<-1>(xB, yB);
        const float ang = -PI2 * (float)q / 4096.f;
        twiddle_apply(yA, ang);
        twiddle_apply(yB, ang);
        #pragma unroll
        for (int u = 0; u < 16; ++u) {
            bufA[phys(q + 256*u)] = yA[u];
            bufB[phys(q + 256*u)] = yB[u];
        }
    }
    __syncthreads();
    {
        const int blk = tid >> 4, a = tid & 15;
        const int base = 256*blk + a;
        float2 xA[16], xB[16], yA[16], yB[16];
        #pragma unroll
        for (int c = 0; c < 16; ++c) {
            xA[c] = bufA[phys(base + 16*c)];
            xB[c] = bufB[phys(base + 16*c)];
        }
        dft16<-1>(xA, yA);
        dft16<-1>(xB, yB);
        const float ang = -PI2 * (float)a / 256.f;
        twiddle_apply(yA, ang);
        twiddle_apply(yB, ang);
        #pragma unroll
        for (int c = 0; c < 16; ++c) {
            bufA[phys(base + 16*c)] = yA[c];
            bufB[phys(base + 16*c)] = yB[c];
        }
    }
    __syncthreads();
    {
        const int blk = tid >> 4, c = tid & 15;
        const int base = 256*blk + 16*c;
        float2 xA[16], xB[16], yA[16], yB[16];
        #pragma unroll
        for (int a2 = 0; a2 < 16; ++a2) {
            xA[a2] = bufA[phys(base + a2)];
            xB[a2] = bufB[phys(base + a2)];
        }
        dft16<-1>(xA, yA);
        dft16<-1>(xB, yB);
        #pragma unroll
        for (int d = 0; d < 16; ++d) {
            bufA[phys(base + d)] = yA[d];
            bufB[phys(base + d)] = yB[d];
        }
    }
    __syncthreads();
    #pragma unroll
    for (int it = 0; it < 16; ++it) {
        const int p  = tid + it * 256;
        const int j  = ((p & 15) << 8) | (p & 0xF0) | (p >> 8);
        const int jn = (FFT_N - j) & (FFT_N - 1);
        const int pn = ((jn & 15) << 8) | (jn & 0xF0) | (jn >> 8);
        const float2 Zj = bufA[phys(p)];
        const float2 Zn = bufA[phys(pn)];
        const float2 Q = { 0.5f*(Zj.x + Zn.x), 0.5f*(Zj.y - Zn.y) };
        const float2 K = { 0.5f*(Zj.y + Zn.y), -0.5f*(Zj.x - Zn.x) };
        const float2 G = { Q.x*K.x + Q.y*K.y, Q.y*K.x - Q.x*K.y };
        const float2 V = bufB[phys(p)];
        bufB[phys(p)] = { G.x*V.x - G.y*V.y, G.x*V.y + G.y*V.x };
    }
    __syncthreads();
    {
        const int blk = tid >> 4, c = tid & 15;
        const int base = 256*blk + 16*c;
        float2 x[16], y[16];
        #pragma unroll
        for (int d = 0; d < 16; ++d) x[d] = bufB[phys(base + d)];
        dft16<1>(x, y);
        #pragma unroll
        for (int p0 = 0; p0 < 16; ++p0) bufB[phys(base + p0)] = y[p0];
    }
    __syncthreads();
    {
        const int blk = tid >> 4, p0 = tid & 15;
        const int base = 256*blk + p0;
        float2 x[16], y[16];
        #pragma unroll
        for (int c = 0; c < 16; ++c) x[c] = bufB[phys(base + 16*c)];
        twiddle_apply(x, PI2 * (float)p0 / 256.f);
        dft16<1>(x, y);
        #pragma unroll
        for (int p1 = 0; p1 < 16; ++p1) bufB[phys(base + 16*p1)] = y[p1];
    }
    __syncthreads();
    {
        const int qq = tid;
        float2 x[16], y[16];
        #pragma unroll
        for (int t = 0; t < 16; ++t) x[t] = bufB[phys(qq + 256*t)];
        twiddle_apply(x, PI2 * (float)qq / 4096.f);
        dft16<1>(x, y);
        const float scale = 0.125f / 4096.f;
        #pragma unroll
        for (int p2 = 0; p2 < 16; ++p2)
            orow[qq + 256*p2] = y[p2].x * scale;
    }
}

// ---------------------------------------------------------------------------
// Transpose + fp16 split: ot fp32 [n][m] -> oth/otl fp16 [m][k=n]
// ---------------------------------------------------------------------------
__global__ __launch_bounds__(256) void transpose_split_kernel(
    const float* __restrict__ ot, ushort* __restrict__ oth,
    ushort* __restrict__ otl)
{
    __shared__ float tile[64][65];
    const int tid = threadIdx.x;
    const int m0  = blockIdx.x * 64;
    const int n0  = blockIdx.y * 64;
    const int r   = tid >> 4;
    const int c   = tid & 15;

    #pragma unroll
    for (int rr = 0; rr < 4; ++rr) {
        const int nl = r + rr * 16;
        float4 v = *(const float4*)(ot + (size_t)(n0 + nl) * M_TOTAL + m0 + c * 4);
        tile[nl][c * 4 + 0] = v.x; tile[nl][c * 4 + 1] = v.y;
        tile[nl][c * 4 + 2] = v.z; tile[nl][c * 4 + 3] = v.w;
    }
    __syncthreads();
    #pragma unroll
    for (int rr = 0; rr < 4; ++rr) {
        const int ml = r + rr * 16;
        ushort4 h, l;
        split1_f16(tile[c * 4 + 0][ml], h.x, l.x);
        split1_f16(tile[c * 4 + 1][ml], h.y, l.y);
        split1_f16(tile[c * 4 + 2][ml], h.z, l.z);
        split1_f16(tile[c * 4 + 3][ml], h.w, l.w);
        *(ushort4*)(oth + (size_t)(m0 + ml) * HIDDEN + n0 + c * 4) = h;
        *(ushort4*)(otl + (size_t)(m0 + ml) * HIDDEN + n0 + c * 4) = l;
    }
}

// ---------------------------------------------------------------------------
// Output GEMM (MFMA fp16): out[m][n] = (oth+otl)[m][:].Woh[n][:] + bo[n]
// Same 1024-thr / 16-wave / 256x256 structure; 2-product product-major.
// A (oth/otl fp16): gload16 pure copy. B (Wo fp32 -> fp16 single).
// ---------------------------------------------------------------------------
__global__ __launch_bounds__(1024, 1) void gemm_out_mfma5(
    const ushort* __restrict__ oth, const ushort* __restrict__ otl,
    const float* __restrict__ Wo, const float* __restrict__ bo,
    float* __restrict__ out)
{
    __shared__ ushort Ah[2][8192], Al[2][8192];   // ot^T tile [256m][32k] hi/lo fp16
    __shared__ ushort Bh[2][8192];                // Wo  tile [256n][32k] fp16

    const int tid  = threadIdx.x;
    const int lane = tid & 63;
    const int wid  = tid >> 6;
    const int wr   = wid >> 2;        // m-dim wave
    const int wc   = wid & 3;         // n-dim wave
    const int m0   = blockIdx.x * 256;
    const int n0   = blockIdx.y * 256;

    const int row  = tid >> 2;
    const int ch   = tid & 3;
    const int chS  = ch ^ ((row >> 1) & 3);
    const int soff = row * 32 + chS * 8;

    const int fr = lane & 15;
    const int fc = lane >> 4;
    const int cc = (fc ^ ((fr >> 1) & 3)) * 8;

    f32x4 acc[4][4];
    #pragma unroll
    for (int rf = 0; rf < 4; ++rf)
        #pragma unroll
        for (int cf = 0; cf < 4; ++cf)
            acc[rf][cf] = (f32x4){0.f, 0.f, 0.f, 0.f};

#if HAVE_GLL
    #define OUT_A_COPY(BUF, GA)                                        \
        gload16(oth + (GA), &Ah[BUF][(size_t)tid * 8]);                \
        gload16(otl + (GA), &Al[BUF][(size_t)tid * 8]);
#else
    #define OUT_A_COPY(BUF, GA)                                        \
        *(f16x8*)&Ah[BUF][(size_t)tid * 8] = *(const f16x8*)(oth + (GA)); \
        *(f16x8*)&Al[BUF][(size_t)tid * 8] = *(const f16x8*)(otl + (GA));
#endif

    #define OUT_STAGE(K0, BUF) {                                               \
        const size_t ga = (size_t)(m0 + row) * HIDDEN + (K0) + (size_t)chS * 8;\
        OUT_A_COPY(BUF, ga);                                                   \
        const float* gb = Wo + (size_t)(n0 + row) * HIDDEN + (K0) + ch * 8;    \
        float4 b0 = *(const float4*)gb, b1 = *(const float4*)(gb + 4);         \
        cvt8_f16(b0, b1, &Bh[BUF][soff]);                                      \
    }

    OUT_STAGE(0, 0);
    __syncthreads();

    for (int ks = 0; ks < HIDDEN / 32; ++ks) {
        const int cur = ks & 1;
        if (ks + 1 < HIDDEN / 32) { OUT_STAGE((ks + 1) * 32, cur ^ 1); }

        {
            const ushort* pAh = Ah[cur];
            const ushort* pAl = Al[cur];
            const ushort* pBh = Bh[cur];
            f16x8 a_h[4], a_l[4], b_h[4];
            #pragma unroll
            for (int rf = 0; rf < 4; ++rf) {
                const int R = wr * 64 + rf * 16 + fr;
                a_h[rf] = *(const f16x8*)(pAh + R * 32 + cc);
                a_l[rf] = *(const f16x8*)(pAl + R * 32 + cc);
            }
            #pragma unroll
            for (int cf = 0; cf < 4; ++cf) {
                const int R = wc * 64 + cf * 16 + fr;
                b_h[cf] = *(const f16x8*)(pBh + R * 32 + cc);
            }
            #pragma unroll
            for (int rf = 0; rf < 4; ++rf)
                #pragma unroll
                for (int cf = 0; cf < 4; ++cf)
                    acc[rf][cf] = __builtin_amdgcn_mfma_f32_16x16x32_f16(a_h[rf], b_h[cf], acc[rf][cf], 0, 0, 0);
            #pragma unroll
            for (int rf = 0; rf < 4; ++rf)
                #pragma unroll
                for (int cf = 0; cf < 4; ++cf)
                    acc[rf][cf] = __builtin_amdgcn_mfma_f32_16x16x32_f16(a_l[rf], b_h[cf], acc[rf][cf], 0, 0, 0);
        }
        __syncthreads();
    }
    #undef OUT_STAGE
    #undef OUT_A_COPY

    // epilogue: D row m_local = wr*64+rf*16+rq*4+r ; col n_local = wc*64+cf*16+fr
    const int rq = lane >> 4;
    float bo_v[4];
    #pragma unroll
    for (int cf = 0; cf < 4; ++cf) bo_v[cf] = bo[n0 + wc * 64 + cf * 16 + fr];
    #pragma unroll
    for (int rf = 0; rf < 4; ++rf) {
        #pragma unroll
        for (int r = 0; r < 4; ++r) {
            const int ml = wr * 64 + rf * 16 + rq * 4 + r;
            float* dst = out + (size_t)(m0 + ml) * HIDDEN + n0 + wc * 64;
            #pragma unroll
            for (int cf = 0; cf < 4; ++cf)
                dst[cf * 16 + fr] = acc[rf][cf][r] + bo_v[cf];
        }
    }
}

// ---------------------------------------------------------------------------
extern "C" void kernel_launch(void* const* d_in, const int* in_sizes, int n_in,
                              void* d_out, int out_size, void* d_ws, size_t ws_size,
                              hipStream_t stream)
{
    const float* x  = (const float*)d_in[0];
    const float* Wq = (const float*)d_in[1];
    const float* bq = (const float*)d_in[2];
    const float* Wk = (const float*)d_in[3];
    const float* bk = (const float*)d_in[4];
    const float* Wv = (const float*)d_in[5];
    const float* bv = (const float*)d_in[6];
    const float* Wo = (const float*)d_in[7];
    const float* bo = (const float*)d_in[8];
    float* out = (float*)d_out;

    const size_t plane = (size_t)HIDDEN * M_TOTAL;   // 16.7M elements
    float* qt = (float*)d_ws;
    float* kt = qt + plane;
    float* vt = kt + plane;
    float* ot = qt;                    // FFT output aliases q plane
    ushort* oth = (ushort*)kt;         // transposed fp16 hi plane (dead k plane)
    ushort* otl = (ushort*)vt;         // lo plane (dead v plane)

    gemm_qkv_mfma5<<<dim3(M_TOTAL / 256, 12), 1024, 0, stream>>>(
        x, Wq, Wk, Wv, bq, bk, bv, qt);

    fft_attn_kernel<<<dim3(HIDDEN * BATCH), 256, 0, stream>>>(qt, kt, vt, ot);

    transpose_split_kernel<<<dim3(M_TOTAL / 64, HIDDEN / 64), 256, 0, stream>>>(
        ot, oth, otl);

    gemm_out_mfma5<<<dim3(M_TOTAL / 256, HIDDEN / 256), 1024, 0, stream>>>(
        oth, otl, Wo, bo, out);
}